// Round 10
// baseline (5389.682 us; speedup 1.0000x reference)
//
#include <hip/hip_runtime.h>
#include <math.h>

typedef __attribute__((ext_vector_type(4))) float f32x4v;
typedef __attribute__((ext_vector_type(8))) __bf16 bf16x8v;

#define SCALE 0.17677669529663687f
#define TOK 131072
#define MCHUNK 32768

__device__ __forceinline__ ushort f2bf(float v){
  uint x = __float_as_uint(v);
  return (ushort)((x + 0x7fffu + ((x >> 16) & 1u)) >> 16);
}
__device__ __forceinline__ float bflo(uint u){ return __uint_as_float(u << 16); }
__device__ __forceinline__ float bfhi(uint u){ return __uint_as_float(u & 0xffff0000u); }

// ---------------- weight f32 -> bf16 convert ----------------
__global__ __launch_bounds__(256) void cvtw_k(const float* __restrict__ src,
    ushort* __restrict__ dst, int n4){
  const int i = blockIdx.x * 256 + threadIdx.x;
  if (i >= n4) return;
  float4 v = ((const float4*)src)[i];
  ushort4 o = { f2bf(v.x), f2bf(v.y), f2bf(v.z), f2bf(v.w) };
  ((ushort4*)dst)[i] = o;
}

// ---- gamma-folded weight convert + c1=sum(gamma*w), c2=sum(beta*w). one wave/row ----
__global__ __launch_bounds__(64) void cvtwg_k(const float* __restrict__ src,
    const float* __restrict__ gma, const float* __restrict__ bta,
    ushort* __restrict__ dst, float* __restrict__ c1, float* __restrict__ c2, int K){
  const int n = blockIdx.x, lane = threadIdx.x;
  const float* sp = src + (long)n * K;
  ushort* dp = dst + (long)n * K;
  float s1 = 0.f, s2 = 0.f;
  for (int k = lane * 4; k < K; k += 256){
    float4 wv = *(const float4*)(sp + k);
    float4 gv = *(const float4*)(gma + k);
    float4 bv = *(const float4*)(bta + k);
    s1 += wv.x * gv.x + wv.y * gv.y + wv.z * gv.z + wv.w * gv.w;
    s2 += wv.x * bv.x + wv.y * bv.y + wv.z * bv.z + wv.w * bv.w;
    ushort4 o = { f2bf(wv.x * gv.x), f2bf(wv.y * gv.y), f2bf(wv.z * gv.z), f2bf(wv.w * gv.w) };
    *(ushort4*)(dp + k) = o;
  }
  #pragma unroll
  for (int o = 1; o < 64; o <<= 1){ s1 += __shfl_xor(s1, o); s2 += __shfl_xor(s2, o); }
  if (lane == 0){ c1[n] = s1; c2[n] = s2; }
}

// ---------------- concat pcd|img -> bf16 A0 [T][512] ----------------
__global__ __launch_bounds__(256) void concat_k(const float* __restrict__ pcd,
    const float* __restrict__ img, ushort* __restrict__ A0){
  const long gid = (long)blockIdx.x * 256 + threadIdx.x;  // over T*512/4
  const long t = gid >> 7;
  const int c4 = (int)(gid & 127) * 4;
  const float* src = (c4 < 256) ? (pcd + t * 256 + c4) : (img + t * 256 + (c4 - 256));
  float4 v = *(const float4*)src;
  ushort4 o = { f2bf(v.x), f2bf(v.y), f2bf(v.z), f2bf(v.w) };
  *(ushort4*)(A0 + t * 512 + c4) = o;
}

// ---------------- row stats over X1 chunk [rows][2048] bf16 -> (mean,rstd) ----------------
__global__ __launch_bounds__(256) void rowstats_k(const ushort* __restrict__ X,
    float* __restrict__ stats){
  const int row = blockIdx.x, tid = threadIdx.x;
  uint4 u = *(const uint4*)(X + (long)row * 2048 + tid * 8);
  float s = 0.f, q = 0.f;
  uint* e = (uint*)&u;
  #pragma unroll
  for (int c = 0; c < 4; ++c){
    float a = bflo(e[c]), b2 = bfhi(e[c]);
    s += a + b2; q += a * a + b2 * b2;
  }
  #pragma unroll
  for (int o = 1; o < 64; o <<= 1){ s += __shfl_xor(s, o); q += __shfl_xor(q, o); }
  __shared__ float ss[4], qs[4];
  if ((tid & 63) == 0){ ss[tid >> 6] = s; qs[tid >> 6] = q; }
  __syncthreads();
  if (tid == 0){
    float S = ss[0] + ss[1] + ss[2] + ss[3];
    float Q = qs[0] + qs[1] + qs[2] + qs[3];
    float mean = S * (1.f / 2048.f);
    float var = Q * (1.f / 2048.f) - mean * mean;
    stats[row * 2] = mean;
    stats[row * 2 + 1] = rsqrtf(var + 1e-5f);
  }
}

// ---------------- row stats over xb bf16 [T][256] -> (mean,rstd) ----------------
__global__ __launch_bounds__(256) void stats256b_k(const ushort* __restrict__ xb,
    float* __restrict__ stats){
  const int lane = threadIdx.x & 63, wd = threadIdx.x >> 6;
  const long row = (long)blockIdx.x * 4 + wd;
  uint2 u = *(const uint2*)(xb + row * 256 + lane * 4);
  float a = bflo(u.x), b2 = bfhi(u.x), c = bflo(u.y), d = bfhi(u.y);
  float s = a + b2 + c + d;
  float q = a * a + b2 * b2 + c * c + d * d;
  #pragma unroll
  for (int o = 1; o < 64; o <<= 1){ s += __shfl_xor(s, o); q += __shfl_xor(q, o); }
  if (lane == 0){
    float mean = s * (1.f / 256.f);
    float var = q * (1.f / 256.f) - mean * mean;
    stats[row * 2] = mean;
    stats[row * 2 + 1] = rsqrtf(var + 1e-5f);
  }
}

// ---------------- bf16 MFMA GEMM: reg-staged BK=64 full-line loop ----------------
// C[M,N] = epi(A[M,K] @ W[N,K]^T). ACT: 0 none,1 leaky,2 gelu. OUTT: 0 f32,1 bf16,2 both.
// RES: 0 none,1 +res,2 +res+pcd. LNEPI: v = rs*acc - mu*rs*c1[n] + c2[n] (then +bias).
template<int ACT, int OUTT, int RES, bool LNEPI>
__global__ __launch_bounds__(256, 3) void gemm_k(
    const ushort* __restrict__ A, const ushort* __restrict__ W,
    const float* __restrict__ bias,
    float* __restrict__ outf, ushort* __restrict__ outb,
    const float* __restrict__ res, const float* __restrict__ pcdp,
    const float* __restrict__ stats, const float* __restrict__ c1v,
    const float* __restrict__ c2v, int N, int K, int gx)
{
  __shared__ ushort SH[18432];          // A: [128][72] | B: [128][72]  (36 KB)
  const int tid = threadIdx.x;
  const int lane = tid & 63, w = tid >> 6;
  const int nwg = gridDim.x;
  int bid = blockIdx.x;
  bid = (bid & 7) * (nwg >> 3) + (bid >> 3);   // XCD-aware, m-major per XCD
  const int mBase = (bid / gx) * 128;
  const int nBase = (bid % gx) * 128;
  const int fr = lane & 15, grp = lane >> 4;
  const int wr = w >> 1, wc = w & 1;

  f32x4v acc[4][4];
  #pragma unroll
  for (int i = 0; i < 4; ++i)
    #pragma unroll
    for (int j = 0; j < 4; ++j) acc[i][j] = (f32x4v){0.f, 0.f, 0.f, 0.f};

  // staging: full 128B line per row: 8 lanes x 16B. 4 loads/matrix cover 32 rows/wave.
  const int rA = w * 32 + (lane >> 3);      // row for g=0 (g adds 8)
  const int sc = (lane & 7) * 8;            // ushort col offset within 64-col tile
  const ushort* Apt = A + (long)(mBase + rA) * K + sc;
  const ushort* Wpt = W + (long)(nBase + rA) * K + sc;
  const long g8K = (long)8 * K;

  uint4 pa[4], pb[4];
  const int NT = K >> 6;
  // prologue: tile 0 -> regs -> LDS; tile 1 -> regs
  #pragma unroll
  for (int g = 0; g < 4; ++g){
    pa[g] = *(const uint4*)(Apt + g * g8K);
    pb[g] = *(const uint4*)(Wpt + g * g8K);
  }
  #pragma unroll
  for (int g = 0; g < 4; ++g){
    *(uint4*)&SH[(rA + g * 8) * 72 + sc] = pa[g];
    *(uint4*)&SH[9216 + (rA + g * 8) * 72 + sc] = pb[g];
  }
  if (NT > 1){
    #pragma unroll
    for (int g = 0; g < 4; ++g){
      pa[g] = *(const uint4*)(Apt + g * g8K + 64);
      pb[g] = *(const uint4*)(Wpt + g * g8K + 64);
    }
  }
  __syncthreads();

  for (int t = 0; t < NT; ++t){
    #pragma unroll
    for (int half = 0; half < 2; ++half){
      const int co = half * 32 + grp * 8;
      bf16x8v af[4], bv[4];
      #pragma unroll
      for (int i = 0; i < 4; ++i)
        af[i] = *(const bf16x8v*)&SH[(wr * 64 + i * 16 + fr) * 72 + co];
      #pragma unroll
      for (int j = 0; j < 4; ++j)
        bv[j] = *(const bf16x8v*)&SH[9216 + (wc * 64 + j * 16 + fr) * 72 + co];
      #pragma unroll
      for (int i = 0; i < 4; ++i)
        #pragma unroll
        for (int j = 0; j < 4; ++j)
          acc[i][j] = __builtin_amdgcn_mfma_f32_16x16x32_bf16(af[i], bv[j], acc[i][j], 0, 0, 0);
    }
    if (t + 1 < NT){
      __syncthreads();                   // all waves done reading tile t
      #pragma unroll
      for (int g = 0; g < 4; ++g){
        *(uint4*)&SH[(rA + g * 8) * 72 + sc] = pa[g];
        *(uint4*)&SH[9216 + (rA + g * 8) * 72 + sc] = pb[g];
      }
      if (t + 2 < NT){
        const long k2 = (long)(t + 2) * 64;
        #pragma unroll
        for (int g = 0; g < 4; ++g){
          pa[g] = *(const uint4*)(Apt + g * g8K + k2);
          pb[g] = *(const uint4*)(Wpt + g * g8K + k2);
        }
      }
      __syncthreads();                   // tile t+1 visible
    }
  }

  // ---- epilogue ----
  float muv[16], rsv[16];
  if (LNEPI){
    #pragma unroll
    for (int i = 0; i < 4; ++i)
      #pragma unroll
      for (int rr = 0; rr < 4; ++rr){
        const int m = mBase + wr * 64 + i * 16 + grp * 4 + rr;
        muv[i * 4 + rr] = stats[m * 2];
        rsv[i * 4 + rr] = stats[m * 2 + 1];
      }
  }
  #pragma unroll
  for (int j = 0; j < 4; ++j){
    const int n = nBase + wc * 64 + j * 16 + fr;
    const float bn = bias[n];
    float c1n = 0.f, c2n = 0.f;
    if (LNEPI){ c1n = c1v[n]; c2n = c2v[n]; }
    #pragma unroll
    for (int i = 0; i < 4; ++i){
      #pragma unroll
      for (int rr = 0; rr < 4; ++rr){
        const long m = mBase + wr * 64 + i * 16 + grp * 4 + rr;
        float v = acc[i][j][rr];
        if (LNEPI) v = rsv[i * 4 + rr] * v - muv[i * 4 + rr] * rsv[i * 4 + rr] * c1n + c2n;
        v += bn;
        if (ACT == 1) v = v > 0.f ? v : 0.01f * v;
        if (ACT == 2) v = 0.5f * v * (1.f + erff(v * 0.70710678118f));
        if (RES >= 1) v += res[m * N + n];
        if (RES == 2) v += pcdp[m * N + n];
        acc[i][j][rr] = v;
        if (OUTT == 0 || OUTT == 2) outf[m * N + n] = v;
      }
    }
  }
  // ---- bf16 output: LDS-staged, single pass, 16B coalesced stores ----
  if (OUTT == 1 || OUTT == 2){
    ushort* eb = SH;   // 32 KB = 128 x 128 bf16 (fits in 36 KB)
    __syncthreads();
    #pragma unroll
    for (int i = 0; i < 4; ++i)
      #pragma unroll
      for (int rr = 0; rr < 4; ++rr){
        const int rl = wr * 64 + i * 16 + grp * 4 + rr;
        #pragma unroll
        for (int j = 0; j < 4; ++j)
          eb[rl * 128 + wc * 64 + j * 16 + fr] = f2bf(acc[i][j][rr]);
      }
    __syncthreads();
    #pragma unroll
    for (int it = 0; it < 8; ++it){
      const int c = it * 256 + tid;            // 2048 chunks of 16B
      const int row = c >> 4, col = (c & 15) * 8;
      *(uint4*)(outb + (long)(mBase + row) * N + nBase + col) =
          *(const uint4*)&eb[row * 128 + col];
    }
  }
}

// ---------------- window attention: one wave per (window, head), scalar ----------------
template<int SHIFT>
__global__ __launch_bounds__(64) void attn_k(const ushort* __restrict__ qkv,
    const float* __restrict__ rpb, ushort* __restrict__ outp)
{
  __shared__ float Kf[64][36];
  __shared__ float Vf[64][36];
  __shared__ float bias_s[225];
  __shared__ int code_s[64];
  const int l = threadIdx.x;
  const int head = blockIdx.x & 7;
  const int bw = blockIdx.x >> 3;
  const int b = bw >> 10, widx = bw & 1023;
  const int wh = widx >> 5, ww = widx & 31;
  for (int i = l; i < 225; i += 64) bias_s[i] = rpb[i * 8 + head];
  const int th = l >> 3, tw = l & 7;
  const int h = wh * 8 + th, w = ww * 8 + tw;
  int mycode = 0;
  if (SHIFT > 0){
    const int rh = (h < 248) ? 0 : ((h < 256 - SHIFT) ? 1 : 2);
    const int rw = (w < 248) ? 0 : ((w < 256 - SHIFT) ? 1 : 2);
    mycode = rh * 3 + rw;
    code_s[l] = mycode;
  }
  const int hs = (h + SHIFT) & 255;
  const int wsm = (w + SHIFT) & 255;
  const long tok = ((long)b * 256 + hs) * 256 + wsm;
  const ushort* qb = qkv + tok * 768 + head * 32;
  float q[32];
  #pragma unroll
  for (int d2 = 0; d2 < 16; ++d2){
    const uint u = *(const uint*)(qb + d2 * 2);
    q[d2 * 2]     = bflo(u) * SCALE;
    q[d2 * 2 + 1] = bfhi(u) * SCALE;
  }
  #pragma unroll
  for (int d2 = 0; d2 < 16; ++d2){
    const uint uk = *(const uint*)(qb + 256 + d2 * 2);
    Kf[l][d2 * 2]     = bflo(uk);
    Kf[l][d2 * 2 + 1] = bfhi(uk);
    const uint uv = *(const uint*)(qb + 512 + d2 * 2);
    Vf[l][d2 * 2]     = bflo(uv);
    Vf[l][d2 * 2 + 1] = bfhi(uv);
  }
  __syncthreads();
  f32x4v o[8];
  #pragma unroll
  for (int d4 = 0; d4 < 8; ++d4) o[d4] = (f32x4v){0.f, 0.f, 0.f, 0.f};
  float sum = 0.f;
  for (int k = 0; k < 64; ++k){
    float s0 = 0.f, s1 = 0.f, s2 = 0.f, s3 = 0.f;
    #pragma unroll
    for (int d4 = 0; d4 < 8; ++d4){
      const f32x4v kv = *(const f32x4v*)&Kf[k][d4 * 4];
      s0 += q[d4 * 4 + 0] * kv[0];
      s1 += q[d4 * 4 + 1] * kv[1];
      s2 += q[d4 * 4 + 2] * kv[2];
      s3 += q[d4 * 4 + 3] * kv[3];
    }
    float s = (s0 + s1) + (s2 + s3);
    s += bias_s[(th - (k >> 3) + 7) * 15 + (tw - (k & 7) + 7)];
    if (SHIFT > 0 && mycode != code_s[k]) s -= 100.f;
    const float p = __expf(s);
    sum += p;
    #pragma unroll
    for (int d4 = 0; d4 < 8; ++d4){
      const f32x4v vv = *(const f32x4v*)&Vf[k][d4 * 4];
      o[d4] += p * vv;
    }
  }
  const float inv = 1.f / sum;
  ushort* ob = outp + tok * 256 + head * 32;
  #pragma unroll
  for (int d4 = 0; d4 < 8; ++d4){
    ushort4 ov = { f2bf(o[d4][0] * inv), f2bf(o[d4][1] * inv),
                   f2bf(o[d4][2] * inv), f2bf(o[d4][3] * inv) };
    *(uint4*)(ob + d4 * 4) = *(uint4*)&ov;
  }
}

extern "C" void kernel_launch(void* const* d_in, const int* in_sizes, int n_in,
                              void* d_out, int out_size, void* d_ws, size_t ws_size,
                              hipStream_t stream){
  const float* pcd    = (const float*)d_in[0];
  const float* img    = (const float*)d_in[1];
  const float* rd_w1  = (const float*)d_in[2];
  const float* rd_b1  = (const float*)d_in[3];
  const float* rd_lng = (const float*)d_in[4];
  const float* rd_lnb = (const float*)d_in[5];
  const float* rd_w2  = (const float*)d_in[6];
  const float* rd_b2  = (const float*)d_in[7];
  const float* n1g    = (const float*)d_in[8];
  const float* n1b    = (const float*)d_in[9];
  const float* qkv_w  = (const float*)d_in[10];
  const float* qkv_b  = (const float*)d_in[11];
  const float* rpb    = (const float*)d_in[12];
  const float* proj_w = (const float*)d_in[13];
  const float* proj_b = (const float*)d_in[14];
  const float* n2g    = (const float*)d_in[15];
  const float* n2b    = (const float*)d_in[16];
  const float* mlp_w1 = (const float*)d_in[17];
  const float* mlp_b1 = (const float*)d_in[18];
  const float* mlp_w2 = (const float*)d_in[19];
  const float* mlp_b2 = (const float*)d_in[20];

  char* ws = (char*)d_ws;
  ushort* w1b    = (ushort*)(ws + 0);                // 2048x512 bf16   2 MB
  ushort* w2g    = (ushort*)(ws + 2097152);          // 256x2048 (γ·w)  1 MB
  ushort* qkvwg  = (ushort*)(ws + 3145728);          // 2x768x256 (γ·w) 0.75 MB
  ushort* projwb = (ushort*)(ws + 3932160);          // 2x256x256       0.25 MB
  ushort* mlp1wg = (ushort*)(ws + 4194304);          // 2x1024x256 (γ·w) 1 MB
  ushort* mlp2wb = (ushort*)(ws + 5242880);          // 2x256x1024      1 MB
  float*  cvec   = (float*)(ws + 6291456);           // 32 KB c1/c2 pool
  float*  w2c1   = cvec,        *w2c2   = cvec + 256;
  float*  qkvc1  = cvec + 512,  *qkvc2  = cvec + 2048;   // 2x768 each
  float*  mlp1c1 = cvec + 3584, *mlp1c2 = cvec + 5632;   // 2x1024 each
  float*  stats  = (float*)(ws + 6324224);           // T x 2 f32  1 MB
  ushort* xb     = (ushort*)(ws + 7372800);          // T x 256 bf16  67 MB
  char*   big    = ws + 74481664;                    // 268,435,456 B region
  ushort* A0     = (ushort*)big;                     // T x 512 bf16 (134 MB)
  ushort* X1c    = (ushort*)(big + 134217728);       // 32768 x 2048 (134 MB)
  ushort* qkvb   = (ushort*)big;                     // T x 768 (201 MB)
  ushort* attno  = (ushort*)(big + 201326592);       // T x 256 (67 MB)
  ushort* hidden = (ushort*)big;                     // T x 1024 (268 MB)
  float* x = (float*)d_out;                          // residual stream f32
  // peak ws use = 74,481,664 + 268,435,456 = 342,917,120 B

  // ---- weight preprocessing ----
  cvtw_k<<<1024, 256, 0, stream>>>(rd_w1, w1b, 262144);
  cvtw_k<<<128,  256, 0, stream>>>(proj_w, projwb, 32768);
  cvtw_k<<<512,  256, 0, stream>>>(mlp_w2, mlp2wb, 131072);
  cvtwg_k<<<256, 64, 0, stream>>>(rd_w2, rd_lng, rd_lnb, w2g, w2c1, w2c2, 2048);
  for (int i = 0; i < 2; ++i){
    cvtwg_k<<<768, 64, 0, stream>>>(qkv_w + i * 196608, n1g + i * 256, n1b + i * 256,
        qkvwg + i * 196608, qkvc1 + i * 768, qkvc2 + i * 768, 256);
    cvtwg_k<<<1024, 64, 0, stream>>>(mlp_w1 + i * 262144, n2g + i * 256, n2b + i * 256,
        mlp1wg + i * 262144, mlp1c1 + i * 1024, mlp1c2 + i * 1024, 256);
  }
  concat_k<<<65536, 256, 0, stream>>>(pcd, img, A0);

  // ---- reduce block, chunked over M ----
  for (int c = 0; c < 4; ++c){
    const long off = (long)c * MCHUNK;
    gemm_k<1,1,0,false><<<4096, 256, 0, stream>>>(A0 + off * 512, w1b, rd_b1,
        nullptr, X1c, nullptr, nullptr, nullptr, nullptr, nullptr, 2048, 512, 16);
    rowstats_k<<<MCHUNK, 256, 0, stream>>>(X1c, stats + off * 2);
    gemm_k<0,2,0,true><<<512, 256, 0, stream>>>(X1c, w2g, rd_b2,
        x + off * 256, xb + off * 256, nullptr, nullptr,
        stats + off * 2, w2c1, w2c2, 256, 2048, 2);
  }
  stats256b_k<<<TOK / 4, 256, 0, stream>>>(xb, stats);

  // ---- Swin layers ----
  for (int i = 0; i < 2; ++i){
    gemm_k<0,1,0,true><<<6144, 256, 0, stream>>>(xb, qkvwg + i * 196608, qkv_b + i * 768,
        nullptr, qkvb, nullptr, nullptr, stats, qkvc1 + i * 768, qkvc2 + i * 768,
        768, 256, 6);
    if (i == 0)
      attn_k<0><<<16384, 64, 0, stream>>>(qkvb, rpb, attno);
    else
      attn_k<4><<<16384, 64, 0, stream>>>(qkvb, rpb + 1800, attno);
    gemm_k<0,2,1,false><<<2048, 256, 0, stream>>>(attno, projwb + i * 65536,
        proj_b + i * 256, x, xb, x, nullptr, nullptr, nullptr, nullptr, 256, 256, 2);
    stats256b_k<<<TOK / 4, 256, 0, stream>>>(xb, stats);
    gemm_k<2,1,0,true><<<8192, 256, 0, stream>>>(xb, mlp1wg + i * 262144,
        mlp_b1 + i * 1024, nullptr, hidden, nullptr, nullptr,
        stats, mlp1c1 + i * 1024, mlp1c2 + i * 1024, 1024, 256, 8);
    if (i == 0){
      gemm_k<0,2,1,false><<<2048, 256, 0, stream>>>(hidden, mlp2wb, mlp_b2,
          x, xb, x, nullptr, nullptr, nullptr, nullptr, 256, 1024, 2);
      stats256b_k<<<TOK / 4, 256, 0, stream>>>(xb, stats);
    } else {
      gemm_k<0,0,2,false><<<2048, 256, 0, stream>>>(hidden, mlp2wb + 262144,
          mlp_b2 + 256, x, nullptr, x, pcd, nullptr, nullptr, nullptr, 256, 1024, 2);
    }
  }
}

// Round 11
// 2316.498 us; speedup vs baseline: 2.3267x; 2.3267x over previous
//
#include <hip/hip_runtime.h>
#include <math.h>

typedef __attribute__((ext_vector_type(4))) float f32x4v;
typedef __attribute__((ext_vector_type(8))) __bf16 bf16x8v;

#define SCALE 0.17677669529663687f
#define TOK 131072
#define MCHUNK 32768

__device__ __forceinline__ ushort f2bf(float v){
  uint x = __float_as_uint(v);
  return (ushort)((x + 0x7fffu + ((x >> 16) & 1u)) >> 16);
}
__device__ __forceinline__ float bflo(uint u){ return __uint_as_float(u << 16); }
__device__ __forceinline__ float bfhi(uint u){ return __uint_as_float(u & 0xffff0000u); }
__device__ __forceinline__ float bf2f(ushort u){ return __uint_as_float((uint)u << 16); }

// ---- async global->LDS, 16B per lane. lds dest = wave-uniform base + lane*16.
__device__ __forceinline__ void gload16(const void* g, void* l){
  __builtin_amdgcn_global_load_lds(
      (const __attribute__((address_space(1))) uint*)g,
      (__attribute__((address_space(3))) uint*)l, 16, 0, 0);
}

// ---------------- weight f32 -> bf16 convert ----------------
__global__ __launch_bounds__(256) void cvtw_k(const float* __restrict__ src,
    ushort* __restrict__ dst, int n4){
  const int i = blockIdx.x * 256 + threadIdx.x;
  if (i >= n4) return;
  float4 v = ((const float4*)src)[i];
  ushort4 o = { f2bf(v.x), f2bf(v.y), f2bf(v.z), f2bf(v.w) };
  ((ushort4*)dst)[i] = o;
}

// ---- gamma-folded weight convert + c1=sum(gamma*w), c2=sum(beta*w). one wave/row ----
__global__ __launch_bounds__(64) void cvtwg_k(const float* __restrict__ src,
    const float* __restrict__ gma, const float* __restrict__ bta,
    ushort* __restrict__ dst, float* __restrict__ c1, float* __restrict__ c2, int K){
  const int n = blockIdx.x, lane = threadIdx.x;
  const float* sp = src + (long)n * K;
  ushort* dp = dst + (long)n * K;
  float s1 = 0.f, s2 = 0.f;
  for (int k = lane * 4; k < K; k += 256){
    float4 wv = *(const float4*)(sp + k);
    float4 gv = *(const float4*)(gma + k);
    float4 bv = *(const float4*)(bta + k);
    s1 += wv.x * gv.x + wv.y * gv.y + wv.z * gv.z + wv.w * gv.w;
    s2 += wv.x * bv.x + wv.y * bv.y + wv.z * bv.z + wv.w * bv.w;
    ushort4 o = { f2bf(wv.x * gv.x), f2bf(wv.y * gv.y), f2bf(wv.z * gv.z), f2bf(wv.w * gv.w) };
    *(ushort4*)(dp + k) = o;
  }
  #pragma unroll
  for (int o = 1; o < 64; o <<= 1){ s1 += __shfl_xor(s1, o); s2 += __shfl_xor(s2, o); }
  if (lane == 0){ c1[n] = s1; c2[n] = s2; }
}

// ---------------- concat pcd|img -> bf16 A0 [T][512] ----------------
__global__ __launch_bounds__(256) void concat_k(const float* __restrict__ pcd,
    const float* __restrict__ img, ushort* __restrict__ A0){
  const long gid = (long)blockIdx.x * 256 + threadIdx.x;  // over T*512/4
  const long t = gid >> 7;
  const int c4 = (int)(gid & 127) * 4;
  const float* src = (c4 < 256) ? (pcd + t * 256 + c4) : (img + t * 256 + (c4 - 256));
  float4 v = *(const float4*)src;
  ushort4 o = { f2bf(v.x), f2bf(v.y), f2bf(v.z), f2bf(v.w) };
  *(ushort4*)(A0 + t * 512 + c4) = o;
}

// ---------------- row stats over X1 chunk [rows][2048] bf16 -> (mean,rstd) ----------------
__global__ __launch_bounds__(256) void rowstats_k(const ushort* __restrict__ X,
    float* __restrict__ stats){
  const int row = blockIdx.x, tid = threadIdx.x;
  uint4 u = *(const uint4*)(X + (long)row * 2048 + tid * 8);
  float s = 0.f, q = 0.f;
  uint* e = (uint*)&u;
  #pragma unroll
  for (int c = 0; c < 4; ++c){
    float a = bflo(e[c]), b2 = bfhi(e[c]);
    s += a + b2; q += a * a + b2 * b2;
  }
  #pragma unroll
  for (int o = 1; o < 64; o <<= 1){ s += __shfl_xor(s, o); q += __shfl_xor(q, o); }
  __shared__ float ss[4], qs[4];
  if ((tid & 63) == 0){ ss[tid >> 6] = s; qs[tid >> 6] = q; }
  __syncthreads();
  if (tid == 0){
    float S = ss[0] + ss[1] + ss[2] + ss[3];
    float Q = qs[0] + qs[1] + qs[2] + qs[3];
    float mean = S * (1.f / 2048.f);
    float var = Q * (1.f / 2048.f) - mean * mean;
    stats[row * 2] = mean;
    stats[row * 2 + 1] = rsqrtf(var + 1e-5f);
  }
}

// ---------------- row stats over xr bf16 [T][256] -> (mean,rstd) ----------------
__global__ __launch_bounds__(256) void stats256b_k(const ushort* __restrict__ xb,
    float* __restrict__ stats){
  const int lane = threadIdx.x & 63, wd = threadIdx.x >> 6;
  const long row = (long)blockIdx.x * 4 + wd;
  uint2 u = *(const uint2*)(xb + row * 256 + lane * 4);
  float a = bflo(u.x), b2 = bfhi(u.x), c = bflo(u.y), d = bfhi(u.y);
  float s = a + b2 + c + d;
  float q = a * a + b2 * b2 + c * c + d * d;
  #pragma unroll
  for (int o = 1; o < 64; o <<= 1){ s += __shfl_xor(s, o); q += __shfl_xor(q, o); }
  if (lane == 0){
    float mean = s * (1.f / 256.f);
    float var = q * (1.f / 256.f) - mean * mean;
    stats[row * 2] = mean;
    stats[row * 2 + 1] = rsqrtf(var + 1e-5f);
  }
}

// ---------------- bf16 MFMA GEMM: round-4 record config (gload_lds, 2-buf, BK=32) ----------------
// C[M,N] = epi(A[M,K] @ W[N,K]^T). ACT: 0 none,1 leaky,2 gelu. OUTT: 0 f32,1 bf16.
// RES: 0 none,1 +res(bf16),2 +res(bf16)+pcd(f32).
// LNEPI: v = rs*acc - mu*rs*c1[n] + c2[n] (then +bias).
template<int ACT, int OUTT, int RES, bool LNEPI>
__global__ __launch_bounds__(256, 2) void gemm_k(
    const ushort* __restrict__ A, const ushort* __restrict__ W,
    const float* __restrict__ bias,
    float* __restrict__ outf, ushort* __restrict__ outb,
    const ushort* __restrict__ res, const float* __restrict__ pcdp,
    const float* __restrict__ stats, const float* __restrict__ c1v,
    const float* __restrict__ c2v, int N, int K, int gx)
{
  __shared__ ushort As[2][128 * 32];
  __shared__ ushort Bs[2][128 * 32];
  const int tid = threadIdx.x;
  const int lane = tid & 63, w = tid >> 6;
  const int nwg = gridDim.x;
  int bid = blockIdx.x;
  bid = (bid & 7) * (nwg >> 3) + (bid >> 3);   // XCD-aware, m-major per XCD
  const int mBase = (bid / gx) * 128;
  const int nBase = (bid % gx) * 128;
  const int fr = lane & 15, grp = lane >> 4;
  const int wr = w >> 1, wc = w & 1;

  f32x4v acc[4][4];
  #pragma unroll
  for (int i = 0; i < 4; ++i)
    #pragma unroll
    for (int j = 0; j < 4; ++j) acc[i][j] = (f32x4v){0.f, 0.f, 0.f, 0.f};

  const ushort* Ap = A + (long)(mBase + w * 32 + (lane >> 2)) * K + (lane & 3) * 8;
  const ushort* Wp = W + (long)(nBase + w * 32 + (lane >> 2)) * K + (lane & 3) * 8;
  const long rowstep = (long)16 * K;
  const int woff = (w * 32) * 32;

  // prologue: stage tile 0 into buf 0
  gload16(Ap, &As[0][woff]);
  gload16(Ap + rowstep, &As[0][woff + 512]);
  gload16(Wp, &Bs[0][woff]);
  gload16(Wp + rowstep, &Bs[0][woff + 512]);
  Ap += 32; Wp += 32;
  __syncthreads();

  int cur = 0;
  for (int kt = 0; kt < K; kt += 32){
    if (kt + 32 < K){
      const int nxt = cur ^ 1;
      gload16(Ap, &As[nxt][woff]);
      gload16(Ap + rowstep, &As[nxt][woff + 512]);
      gload16(Wp, &Bs[nxt][woff]);
      gload16(Wp + rowstep, &Bs[nxt][woff + 512]);
      Ap += 32; Wp += 32;
    }
    bf16x8v af[4], bv[4];
    #pragma unroll
    for (int i = 0; i < 4; ++i)
      af[i] = *(const bf16x8v*)&As[cur][(wr * 64 + i * 16 + fr) * 32 + grp * 8];
    #pragma unroll
    for (int j = 0; j < 4; ++j)
      bv[j] = *(const bf16x8v*)&Bs[cur][(wc * 64 + j * 16 + fr) * 32 + grp * 8];
    #pragma unroll
    for (int i = 0; i < 4; ++i)
      #pragma unroll
      for (int j = 0; j < 4; ++j)
        acc[i][j] = __builtin_amdgcn_mfma_f32_16x16x32_bf16(af[i], bv[j], acc[i][j], 0, 0, 0);
    __syncthreads();   // drains next-tile loads; frees cur for restaging
    cur ^= 1;
  }

  // ---- epilogue ----
  float muv[16], rsv[16];
  if (LNEPI){
    #pragma unroll
    for (int i = 0; i < 4; ++i)
      #pragma unroll
      for (int rr = 0; rr < 4; ++rr){
        const int m = mBase + wr * 64 + i * 16 + grp * 4 + rr;
        muv[i * 4 + rr] = stats[m * 2];
        rsv[i * 4 + rr] = stats[m * 2 + 1];
      }
  }
  #pragma unroll
  for (int j = 0; j < 4; ++j){
    const int n = nBase + wc * 64 + j * 16 + fr;
    const float bn = bias[n];
    float c1n = 0.f, c2n = 0.f;
    if (LNEPI){ c1n = c1v[n]; c2n = c2v[n]; }
    #pragma unroll
    for (int i = 0; i < 4; ++i){
      #pragma unroll
      for (int rr = 0; rr < 4; ++rr){
        const long m = mBase + wr * 64 + i * 16 + grp * 4 + rr;
        float v = acc[i][j][rr];
        if (LNEPI) v = rsv[i * 4 + rr] * v - muv[i * 4 + rr] * rsv[i * 4 + rr] * c1n + c2n;
        v += bn;
        if (ACT == 1) v = v > 0.f ? v : 0.01f * v;
        if (ACT == 2) v = 0.5f * v * (1.f + erff(v * 0.70710678118f));
        if (RES >= 1) v += bf2f(res[m * N + n]);
        if (RES == 2) v += pcdp[m * N + n];
        acc[i][j][rr] = v;
        if (OUTT == 0) outf[m * N + n] = v;
      }
    }
  }
  // ---- bf16 output: LDS-staged, 16B coalesced stores (two 64x128 passes) ----
  if (OUTT == 1){
    ushort* eb = &As[0][0];   // 16 KB = 64 x 128 bf16
    __syncthreads();
    #pragma unroll
    for (int p = 0; p < 2; ++p){
      if (wr == p){
        #pragma unroll
        for (int i = 0; i < 4; ++i)
          #pragma unroll
          for (int rr = 0; rr < 4; ++rr){
            const int rl = i * 16 + grp * 4 + rr;
            #pragma unroll
            for (int j = 0; j < 4; ++j)
              eb[rl * 128 + wc * 64 + j * 16 + fr] = f2bf(acc[i][j][rr]);
          }
      }
      __syncthreads();
      #pragma unroll
      for (int it = 0; it < 4; ++it){
        const int c = it * 256 + tid;           // 1024 chunks of 16B
        const int row = c >> 4, col = (c & 15) * 8;
        *(uint4*)(outb + (long)(mBase + p * 64 + row) * N + nBase + col) =
            *(const uint4*)&eb[row * 128 + col];
      }
      __syncthreads();
    }
  }
}

// ---------------- window attention: one block = (window, 4-head group), 4 waves ----------------
// Cooperative coalesced K/V staging into LDS (f32), then per-wave scalar softmax (proven path).
template<int SHIFT>
__global__ __launch_bounds__(256) void attn_k(const ushort* __restrict__ qkv,
    const float* __restrict__ rpb, ushort* __restrict__ outp)
{
  __shared__ float Kf[64][132];   // [token][4 heads x 32d], pad 4
  __shared__ float Vf[64][132];
  __shared__ float bias_s[4][226];
  __shared__ int code_s[64];
  const int tid = threadIdx.x;
  const int lane = tid & 63, wid = tid >> 6;
  const int hg = blockIdx.x & 1;
  const int bw = blockIdx.x >> 1;           // window id
  const int b = bw >> 10, widx = bw & 1023;
  const int wh = widx >> 5, ww = widx & 31;
  const int head = hg * 4 + wid;

  // per-wave bias table for its head
  for (int i = lane; i < 225; i += 64) bias_s[wid][i] = rpb[i * 8 + head];

  // region codes per token (thread t<64 owns token t)
  if (SHIFT > 0 && tid < 64){
    const int hh = wh * 8 + (tid >> 3), wwp = ww * 8 + (tid & 7);
    const int rh = (hh < 248) ? 0 : ((hh < 256 - SHIFT) ? 1 : 2);
    const int rw = (wwp < 248) ? 0 : ((wwp < 256 - SHIFT) ? 1 : 2);
    code_s[tid] = rh * 3 + rw;
  }

  // cooperative K/V staging: this head-group's 128-ushort slices, fully coalesced
  #pragma unroll
  for (int it = 0; it < 4; ++it){
    const int c = it * 256 + tid;             // 1024 chunks over [64 rows][16 parts]
    const int row = c >> 4, part = c & 15;
    const int hs = (wh * 8 + (row >> 3) + SHIFT) & 255;
    const int wsm = (ww * 8 + (row & 7) + SHIFT) & 255;
    const long tk = ((long)b * 256 + hs) * 256 + wsm;
    const uint4 ku = *(const uint4*)(qkv + tk * 768 + 256 + hg * 128 + part * 8);
    const uint4 vu = *(const uint4*)(qkv + tk * 768 + 512 + hg * 128 + part * 8);
    const uint* ke = (const uint*)&ku;
    const uint* ve = (const uint*)&vu;
    #pragma unroll
    for (int e = 0; e < 4; ++e){
      Kf[row][part * 8 + e * 2]     = bflo(ke[e]);
      Kf[row][part * 8 + e * 2 + 1] = bfhi(ke[e]);
      Vf[row][part * 8 + e * 2]     = bflo(ve[e]);
      Vf[row][part * 8 + e * 2 + 1] = bfhi(ve[e]);
    }
  }

  // per-lane q load (this wave's head slice of its token)
  const int th = lane >> 3, tw = lane & 7;
  const int h = wh * 8 + th, w = ww * 8 + tw;
  int mycode = 0;
  if (SHIFT > 0){
    const int rh = (h < 248) ? 0 : ((h < 256 - SHIFT) ? 1 : 2);
    const int rw = (w < 248) ? 0 : ((w < 256 - SHIFT) ? 1 : 2);
    mycode = rh * 3 + rw;
  }
  const int hs = (h + SHIFT) & 255;
  const int wsm = (w + SHIFT) & 255;
  const long tok = ((long)b * 256 + hs) * 256 + wsm;
  const ushort* qb = qkv + tok * 768 + head * 32;
  float q[32];
  #pragma unroll
  for (int d2 = 0; d2 < 16; ++d2){
    const uint u = *(const uint*)(qb + d2 * 2);
    q[d2 * 2]     = bflo(u) * SCALE;
    q[d2 * 2 + 1] = bfhi(u) * SCALE;
  }
  __syncthreads();

  const int hb = wid * 32;
  f32x4v o[8];
  #pragma unroll
  for (int d4 = 0; d4 < 8; ++d4) o[d4] = (f32x4v){0.f, 0.f, 0.f, 0.f};
  float sum = 0.f;
  for (int k = 0; k < 64; ++k){
    float s0 = 0.f, s1 = 0.f, s2 = 0.f, s3 = 0.f;
    #pragma unroll
    for (int d4 = 0; d4 < 8; ++d4){
      const f32x4v kv = *(const f32x4v*)&Kf[k][hb + d4 * 4];
      s0 += q[d4 * 4 + 0] * kv[0];
      s1 += q[d4 * 4 + 1] * kv[1];
      s2 += q[d4 * 4 + 2] * kv[2];
      s3 += q[d4 * 4 + 3] * kv[3];
    }
    float s = (s0 + s1) + (s2 + s3);
    s += bias_s[wid][(th - (k >> 3) + 7) * 15 + (tw - (k & 7) + 7)];
    if (SHIFT > 0 && mycode != code_s[k]) s -= 100.f;
    const float p = __expf(s);
    sum += p;
    #pragma unroll
    for (int d4 = 0; d4 < 8; ++d4){
      const f32x4v vv = *(const f32x4v*)&Vf[k][hb + d4 * 4];
      o[d4] += p * vv;
    }
  }
  const float inv = 1.f / sum;
  ushort* ob = outp + tok * 256 + head * 32;
  #pragma unroll
  for (int d4 = 0; d4 < 8; ++d4){
    ushort4 ov = { f2bf(o[d4][0] * inv), f2bf(o[d4][1] * inv),
                   f2bf(o[d4][2] * inv), f2bf(o[d4][3] * inv) };
    *(ushort4*)(ob + d4 * 4) = ov;
  }
}

extern "C" void kernel_launch(void* const* d_in, const int* in_sizes, int n_in,
                              void* d_out, int out_size, void* d_ws, size_t ws_size,
                              hipStream_t stream){
  const float* pcd    = (const float*)d_in[0];
  const float* img    = (const float*)d_in[1];
  const float* rd_w1  = (const float*)d_in[2];
  const float* rd_b1  = (const float*)d_in[3];
  const float* rd_lng = (const float*)d_in[4];
  const float* rd_lnb = (const float*)d_in[5];
  const float* rd_w2  = (const float*)d_in[6];
  const float* rd_b2  = (const float*)d_in[7];
  const float* n1g    = (const float*)d_in[8];
  const float* n1b    = (const float*)d_in[9];
  const float* qkv_w  = (const float*)d_in[10];
  const float* qkv_b  = (const float*)d_in[11];
  const float* rpb    = (const float*)d_in[12];
  const float* proj_w = (const float*)d_in[13];
  const float* proj_b = (const float*)d_in[14];
  const float* n2g    = (const float*)d_in[15];
  const float* n2b    = (const float*)d_in[16];
  const float* mlp_w1 = (const float*)d_in[17];
  const float* mlp_b1 = (const float*)d_in[18];
  const float* mlp_w2 = (const float*)d_in[19];
  const float* mlp_b2 = (const float*)d_in[20];

  char* ws = (char*)d_ws;
  ushort* w1b    = (ushort*)(ws + 0);                // 2048x512 bf16   2 MB
  ushort* w2g    = (ushort*)(ws + 2097152);          // 256x2048 (γ·w)  1 MB
  ushort* qkvwg  = (ushort*)(ws + 3145728);          // 2x768x256 (γ·w) 0.75 MB
  ushort* projwb = (ushort*)(ws + 3932160);          // 2x256x256       0.25 MB
  ushort* mlp1wg = (ushort*)(ws + 4194304);          // 2x1024x256 (γ·w) 1 MB
  ushort* mlp2wb = (ushort*)(ws + 5242880);          // 2x256x1024      1 MB
  float*  cvec   = (float*)(ws + 6291456);           // 32 KB c1/c2 pool
  float*  w2c1   = cvec,        *w2c2   = cvec + 256;
  float*  qkvc1  = cvec + 512,  *qkvc2  = cvec + 2048;   // 2x768 each
  float*  mlp1c1 = cvec + 3584, *mlp1c2 = cvec + 5632;   // 2x1024 each
  float*  stats  = (float*)(ws + 6324224);           // T x 2 f32  1 MB
  ushort* xr     = (ushort*)(ws + 7372800);          // residual, T x 256 bf16  67 MB
  char*   big    = ws + 74481664;                    // 268,435,456 B region
  ushort* A0     = (ushort*)big;                     // T x 512 bf16 (134 MB)
  ushort* X1c    = (ushort*)(big + 134217728);       // 32768 x 2048 (134 MB)
  ushort* qkvb   = (ushort*)big;                     // T x 768 (201 MB)
  ushort* attno  = (ushort*)(big + 201326592);       // T x 256 (67 MB)
  ushort* hidden = (ushort*)big;                     // T x 1024 (268 MB)
  float* xout = (float*)d_out;                       // final output f32
  // peak ws use = 74,481,664 + 268,435,456 = 342,917,120 B

  // ---- weight preprocessing ----
  cvtw_k<<<1024, 256, 0, stream>>>(rd_w1, w1b, 262144);
  cvtw_k<<<128,  256, 0, stream>>>(proj_w, projwb, 32768);
  cvtw_k<<<512,  256, 0, stream>>>(mlp_w2, mlp2wb, 131072);
  cvtwg_k<<<256, 64, 0, stream>>>(rd_w2, rd_lng, rd_lnb, w2g, w2c1, w2c2, 2048);
  for (int i = 0; i < 2; ++i){
    cvtwg_k<<<768, 64, 0, stream>>>(qkv_w + i * 196608, n1g + i * 256, n1b + i * 256,
        qkvwg + i * 196608, qkvc1 + i * 768, qkvc2 + i * 768, 256);
    cvtwg_k<<<1024, 64, 0, stream>>>(mlp_w1 + i * 262144, n2g + i * 256, n2b + i * 256,
        mlp1wg + i * 262144, mlp1c1 + i * 1024, mlp1c2 + i * 1024, 256);
  }
  concat_k<<<65536, 256, 0, stream>>>(pcd, img, A0);

  // ---- reduce block, chunked over M ----
  for (int c = 0; c < 4; ++c){
    const long off = (long)c * MCHUNK;
    gemm_k<1,1,0,false><<<4096, 256, 0, stream>>>(A0 + off * 512, w1b, rd_b1,
        nullptr, X1c, nullptr, nullptr, nullptr, nullptr, nullptr, 2048, 512, 16);
    rowstats_k<<<MCHUNK, 256, 0, stream>>>(X1c, stats + off * 2);
    gemm_k<0,1,0,true><<<512, 256, 0, stream>>>(X1c, w2g, rd_b2,
        nullptr, xr + off * 256, nullptr, nullptr,
        stats + off * 2, w2c1, w2c2, 256, 2048, 2);
  }
  stats256b_k<<<TOK / 4, 256, 0, stream>>>(xr, stats);

  // ---- Swin layers ----
  for (int i = 0; i < 2; ++i){
    gemm_k<0,1,0,true><<<6144, 256, 0, stream>>>(xr, qkvwg + i * 196608, qkv_b + i * 768,
        nullptr, qkvb, nullptr, nullptr, stats, qkvc1 + i * 768, qkvc2 + i * 768,
        768, 256, 6);
    if (i == 0)
      attn_k<0><<<4096, 256, 0, stream>>>(qkvb, rpb, attno);
    else
      attn_k<4><<<4096, 256, 0, stream>>>(qkvb, rpb + 1800, attno);
    // xr += attno @ proj^T + b (in-place bf16 residual)
    gemm_k<0,1,1,false><<<2048, 256, 0, stream>>>(attno, projwb + i * 65536,
        proj_b + i * 256, nullptr, xr, xr, nullptr, nullptr, nullptr, nullptr, 256, 256, 2);
    stats256b_k<<<TOK / 4, 256, 0, stream>>>(xr, stats);
    gemm_k<2,1,0,true><<<8192, 256, 0, stream>>>(xr, mlp1wg + i * 262144,
        mlp_b1 + i * 1024, nullptr, hidden, nullptr, nullptr,
        stats, mlp1c1 + i * 1024, mlp1c2 + i * 1024, 1024, 256, 8);
    if (i == 0){
      gemm_k<0,1,1,false><<<2048, 256, 0, stream>>>(hidden, mlp2wb, mlp_b2,
          nullptr, xr, xr, nullptr, nullptr, nullptr, nullptr, 256, 1024, 2);
      stats256b_k<<<TOK / 4, 256, 0, stream>>>(xr, stats);
    } else {
      // final: out = xr + hidden @ mlp2^T + b2 + pcd   (f32)
      gemm_k<0,0,2,false><<<2048, 256, 0, stream>>>(hidden, mlp2wb + 262144,
          mlp_b2 + 256, xout, nullptr, xr, pcd, nullptr, nullptr, nullptr, 256, 1024, 2);
    }
  }
}

// Round 13
// 2232.753 us; speedup vs baseline: 2.4139x; 1.0375x over previous
//
#include <hip/hip_runtime.h>
#include <math.h>

typedef __attribute__((ext_vector_type(4))) float f32x4v;
typedef __attribute__((ext_vector_type(8))) __bf16 bf16x8v;
typedef __attribute__((ext_vector_type(2))) uint u32x2v;
typedef __attribute__((ext_vector_type(4))) uint u32x4v;

#define SCALE 0.17677669529663687f
#define TOK 131072
#define MCHUNK 32768

__device__ __forceinline__ ushort f2bf(float v){
  uint x = __float_as_uint(v);
  return (ushort)((x + 0x7fffu + ((x >> 16) & 1u)) >> 16);
}
__device__ __forceinline__ float bflo(uint u){ return __uint_as_float(u << 16); }
__device__ __forceinline__ float bfhi(uint u){ return __uint_as_float(u & 0xffff0000u); }
__device__ __forceinline__ float bf2f(ushort u){ return __uint_as_float((uint)u << 16); }

// ---- async global->LDS, 16B per lane. lds dest = wave-uniform base + lane*16.
__device__ __forceinline__ void gload16(const void* g, void* l){
  __builtin_amdgcn_global_load_lds(
      (const __attribute__((address_space(1))) uint*)g,
      (__attribute__((address_space(3))) uint*)l, 16, 0, 0);
}

// ---------------- weight f32 -> bf16 convert ----------------
__global__ __launch_bounds__(256) void cvtw_k(const float* __restrict__ src,
    ushort* __restrict__ dst, int n4){
  const int i = blockIdx.x * 256 + threadIdx.x;
  if (i >= n4) return;
  float4 v = ((const float4*)src)[i];
  ushort4 o = { f2bf(v.x), f2bf(v.y), f2bf(v.z), f2bf(v.w) };
  ((ushort4*)dst)[i] = o;
}

// ---- gamma-folded weight convert + c1=sum(gamma*w), c2=sum(beta*w). one wave/row ----
__global__ __launch_bounds__(64) void cvtwg_k(const float* __restrict__ src,
    const float* __restrict__ gma, const float* __restrict__ bta,
    ushort* __restrict__ dst, float* __restrict__ c1, float* __restrict__ c2, int K){
  const int n = blockIdx.x, lane = threadIdx.x;
  const float* sp = src + (long)n * K;
  ushort* dp = dst + (long)n * K;
  float s1 = 0.f, s2 = 0.f;
  for (int k = lane * 4; k < K; k += 256){
    float4 wv = *(const float4*)(sp + k);
    float4 gv = *(const float4*)(gma + k);
    float4 bv = *(const float4*)(bta + k);
    s1 += wv.x * gv.x + wv.y * gv.y + wv.z * gv.z + wv.w * gv.w;
    s2 += wv.x * bv.x + wv.y * bv.y + wv.z * bv.z + wv.w * bv.w;
    ushort4 o = { f2bf(wv.x * gv.x), f2bf(wv.y * gv.y), f2bf(wv.z * gv.z), f2bf(wv.w * gv.w) };
    *(ushort4*)(dp + k) = o;
  }
  #pragma unroll
  for (int o = 1; o < 64; o <<= 1){ s1 += __shfl_xor(s1, o); s2 += __shfl_xor(s2, o); }
  if (lane == 0){ c1[n] = s1; c2[n] = s2; }
}

// ---------------- concat pcd|img -> bf16 A0 [T][512] ----------------
__global__ __launch_bounds__(256) void concat_k(const float* __restrict__ pcd,
    const float* __restrict__ img, ushort* __restrict__ A0){
  const long gid = (long)blockIdx.x * 256 + threadIdx.x;  // over T*512/4
  const long t = gid >> 7;
  const int c4 = (int)(gid & 127) * 4;
  const float* src = (c4 < 256) ? (pcd + t * 256 + c4) : (img + t * 256 + (c4 - 256));
  float4 v = *(const float4*)src;
  ushort4 o = { f2bf(v.x), f2bf(v.y), f2bf(v.z), f2bf(v.w) };
  __builtin_nontemporal_store(*(u32x2v*)&o, (u32x2v*)(A0 + t * 512 + c4));
}

// ---------------- row stats over X1 chunk [rows][2048] bf16 -> (mean,rstd) ----------------
__global__ __launch_bounds__(256) void rowstats_k(const ushort* __restrict__ X,
    float* __restrict__ stats){
  const int row = blockIdx.x, tid = threadIdx.x;
  uint4 u = *(const uint4*)(X + (long)row * 2048 + tid * 8);
  float s = 0.f, q = 0.f;
  uint* e = (uint*)&u;
  #pragma unroll
  for (int c = 0; c < 4; ++c){
    float a = bflo(e[c]), b2 = bfhi(e[c]);
    s += a + b2; q += a * a + b2 * b2;
  }
  #pragma unroll
  for (int o = 1; o < 64; o <<= 1){ s += __shfl_xor(s, o); q += __shfl_xor(q, o); }
  __shared__ float ss[4], qs[4];
  if ((tid & 63) == 0){ ss[tid >> 6] = s; qs[tid >> 6] = q; }
  __syncthreads();
  if (tid == 0){
    float S = ss[0] + ss[1] + ss[2] + ss[3];
    float Q = qs[0] + qs[1] + qs[2] + qs[3];
    float mean = S * (1.f / 2048.f);
    float var = Q * (1.f / 2048.f) - mean * mean;
    stats[row * 2] = mean;
    stats[row * 2 + 1] = rsqrtf(var + 1e-5f);
  }
}

// ---------------- row stats over xr bf16 [T][256] -> (mean,rstd) ----------------
__global__ __launch_bounds__(256) void stats256b_k(const ushort* __restrict__ xb,
    float* __restrict__ stats){
  const int lane = threadIdx.x & 63, wd = threadIdx.x >> 6;
  const long row = (long)blockIdx.x * 4 + wd;
  uint2 u = *(const uint2*)(xb + row * 256 + lane * 4);
  float a = bflo(u.x), b2 = bfhi(u.x), c = bflo(u.y), d = bfhi(u.y);
  float s = a + b2 + c + d;
  float q = a * a + b2 * b2 + c * c + d * d;
  #pragma unroll
  for (int o = 1; o < 64; o <<= 1){ s += __shfl_xor(s, o); q += __shfl_xor(q, o); }
  if (lane == 0){
    float mean = s * (1.f / 256.f);
    float var = q * (1.f / 256.f) - mean * mean;
    stats[row * 2] = mean;
    stats[row * 2 + 1] = rsqrtf(var + 1e-5f);
  }
}

// ---------------- bf16 MFMA GEMM: record config + nontemporal output stores ----------------
// C[M,N] = epi(A[M,K] @ W[N,K]^T). ACT: 0 none,1 leaky,2 gelu. OUTT: 0 f32,1 bf16.
// RES: 0 none,1 +res(bf16),2 +res(bf16)+pcd(f32).
// LNEPI: v = rs*acc - mu*rs*c1[n] + c2[n] (then +bias).
template<int ACT, int OUTT, int RES, bool LNEPI>
__global__ __launch_bounds__(256, 2) void gemm_k(
    const ushort* __restrict__ A, const ushort* __restrict__ W,
    const float* __restrict__ bias,
    float* __restrict__ outf, ushort* __restrict__ outb,
    const ushort* __restrict__ res, const float* __restrict__ pcdp,
    const float* __restrict__ stats, const float* __restrict__ c1v,
    const float* __restrict__ c2v, int N, int K, int gx)
{
  __shared__ ushort As[2][128 * 32];
  __shared__ ushort Bs[2][128 * 32];
  const int tid = threadIdx.x;
  const int lane = tid & 63, w = tid >> 6;
  const int nwg = gridDim.x;
  int bid = blockIdx.x;
  bid = (bid & 7) * (nwg >> 3) + (bid >> 3);   // XCD-aware, m-major per XCD
  const int mBase = (bid / gx) * 128;
  const int nBase = (bid % gx) * 128;
  const int fr = lane & 15, grp = lane >> 4;
  const int wr = w >> 1, wc = w & 1;

  f32x4v acc[4][4];
  #pragma unroll
  for (int i = 0; i < 4; ++i)
    #pragma unroll
    for (int j = 0; j < 4; ++j) acc[i][j] = (f32x4v){0.f, 0.f, 0.f, 0.f};

  const ushort* Ap = A + (long)(mBase + w * 32 + (lane >> 2)) * K + (lane & 3) * 8;
  const ushort* Wp = W + (long)(nBase + w * 32 + (lane >> 2)) * K + (lane & 3) * 8;
  const long rowstep = (long)16 * K;
  const int woff = (w * 32) * 32;

  // prologue: stage tile 0 into buf 0
  gload16(Ap, &As[0][woff]);
  gload16(Ap + rowstep, &As[0][woff + 512]);
  gload16(Wp, &Bs[0][woff]);
  gload16(Wp + rowstep, &Bs[0][woff + 512]);
  Ap += 32; Wp += 32;
  __syncthreads();

  int cur = 0;
  for (int kt = 0; kt < K; kt += 32){
    if (kt + 32 < K){
      const int nxt = cur ^ 1;
      gload16(Ap, &As[nxt][woff]);
      gload16(Ap + rowstep, &As[nxt][woff + 512]);
      gload16(Wp, &Bs[nxt][woff]);
      gload16(Wp + rowstep, &Bs[nxt][woff + 512]);
      Ap += 32; Wp += 32;
    }
    bf16x8v af[4], bv[4];
    #pragma unroll
    for (int i = 0; i < 4; ++i)
      af[i] = *(const bf16x8v*)&As[cur][(wr * 64 + i * 16 + fr) * 32 + grp * 8];
    #pragma unroll
    for (int j = 0; j < 4; ++j)
      bv[j] = *(const bf16x8v*)&Bs[cur][(wc * 64 + j * 16 + fr) * 32 + grp * 8];
    #pragma unroll
    for (int i = 0; i < 4; ++i)
      #pragma unroll
      for (int j = 0; j < 4; ++j)
        acc[i][j] = __builtin_amdgcn_mfma_f32_16x16x32_bf16(af[i], bv[j], acc[i][j], 0, 0, 0);
    __syncthreads();   // drains next-tile loads; frees cur for restaging
    cur ^= 1;
  }

  // ---- epilogue ----
  float muv[16], rsv[16];
  if (LNEPI){
    #pragma unroll
    for (int i = 0; i < 4; ++i)
      #pragma unroll
      for (int rr = 0; rr < 4; ++rr){
        const int m = mBase + wr * 64 + i * 16 + grp * 4 + rr;
        muv[i * 4 + rr] = stats[m * 2];
        rsv[i * 4 + rr] = stats[m * 2 + 1];
      }
  }
  #pragma unroll
  for (int j = 0; j < 4; ++j){
    const int n = nBase + wc * 64 + j * 16 + fr;
    const float bn = bias[n];
    float c1n = 0.f, c2n = 0.f;
    if (LNEPI){ c1n = c1v[n]; c2n = c2v[n]; }
    #pragma unroll
    for (int i = 0; i < 4; ++i){
      #pragma unroll
      for (int rr = 0; rr < 4; ++rr){
        const long m = mBase + wr * 64 + i * 16 + grp * 4 + rr;
        float v = acc[i][j][rr];
        if (LNEPI) v = rsv[i * 4 + rr] * v - muv[i * 4 + rr] * rsv[i * 4 + rr] * c1n + c2n;
        v += bn;
        if (ACT == 1) v = v > 0.f ? v : 0.01f * v;
        if (ACT == 2) v = 0.5f * v * (1.f + erff(v * 0.70710678118f));
        if (RES >= 1) v += bf2f(res[m * N + n]);
        if (RES == 2) v += pcdp[m * N + n];
        acc[i][j][rr] = v;
        if (OUTT == 0) __builtin_nontemporal_store(v, &outf[m * N + n]);
      }
    }
  }
  // ---- bf16 output: LDS-staged, 16B coalesced nontemporal stores ----
  if (OUTT == 1){
    ushort* eb = &As[0][0];   // 16 KB = 64 x 128 bf16
    __syncthreads();
    #pragma unroll
    for (int p = 0; p < 2; ++p){
      if (wr == p){
        #pragma unroll
        for (int i = 0; i < 4; ++i)
          #pragma unroll
          for (int rr = 0; rr < 4; ++rr){
            const int rl = i * 16 + grp * 4 + rr;
            #pragma unroll
            for (int j = 0; j < 4; ++j)
              eb[rl * 128 + wc * 64 + j * 16 + fr] = f2bf(acc[i][j][rr]);
          }
      }
      __syncthreads();
      #pragma unroll
      for (int it = 0; it < 4; ++it){
        const int c = it * 256 + tid;           // 1024 chunks of 16B
        const int row = c >> 4, col = (c & 15) * 8;
        const u32x4v val = *(const u32x4v*)&eb[row * 128 + col];
        __builtin_nontemporal_store(val,
            (u32x4v*)(outb + (long)(mBase + p * 64 + row) * N + nBase + col));
      }
      __syncthreads();
    }
  }
}

// ---------------- window attention: one block = (window, 4-head group), 4 waves ----------------
template<int SHIFT>
__global__ __launch_bounds__(256) void attn_k(const ushort* __restrict__ qkv,
    const float* __restrict__ rpb, ushort* __restrict__ outp)
{
  __shared__ float Kf[64][132];   // [token][4 heads x 32d], pad 4
  __shared__ float Vf[64][132];
  __shared__ float bias_s[4][226];
  __shared__ int code_s[64];
  const int tid = threadIdx.x;
  const int lane = tid & 63, wid = tid >> 6;
  const int hg = blockIdx.x & 1;
  const int bw = blockIdx.x >> 1;           // window id
  const int b = bw >> 10, widx = bw & 1023;
  const int wh = widx >> 5, ww = widx & 31;
  const int head = hg * 4 + wid;

  for (int i = lane; i < 225; i += 64) bias_s[wid][i] = rpb[i * 8 + head];

  if (SHIFT > 0 && tid < 64){
    const int hh = wh * 8 + (tid >> 3), wwp = ww * 8 + (tid & 7);
    const int rh = (hh < 248) ? 0 : ((hh < 256 - SHIFT) ? 1 : 2);
    const int rw = (wwp < 248) ? 0 : ((wwp < 256 - SHIFT) ? 1 : 2);
    code_s[tid] = rh * 3 + rw;
  }

  #pragma unroll
  for (int it = 0; it < 4; ++it){
    const int c = it * 256 + tid;             // 1024 chunks over [64 rows][16 parts]
    const int row = c >> 4, part = c & 15;
    const int hs = (wh * 8 + (row >> 3) + SHIFT) & 255;
    const int wsm = (ww * 8 + (row & 7) + SHIFT) & 255;
    const long tk = ((long)b * 256 + hs) * 256 + wsm;
    const uint4 ku = *(const uint4*)(qkv + tk * 768 + 256 + hg * 128 + part * 8);
    const uint4 vu = *(const uint4*)(qkv + tk * 768 + 512 + hg * 128 + part * 8);
    const uint* ke = (const uint*)&ku;
    const uint* ve = (const uint*)&vu;
    #pragma unroll
    for (int e = 0; e < 4; ++e){
      Kf[row][part * 8 + e * 2]     = bflo(ke[e]);
      Kf[row][part * 8 + e * 2 + 1] = bfhi(ke[e]);
      Vf[row][part * 8 + e * 2]     = bflo(ve[e]);
      Vf[row][part * 8 + e * 2 + 1] = bfhi(ve[e]);
    }
  }

  const int th = lane >> 3, tw = lane & 7;
  const int h = wh * 8 + th, w = ww * 8 + tw;
  int mycode = 0;
  if (SHIFT > 0){
    const int rh = (h < 248) ? 0 : ((h < 256 - SHIFT) ? 1 : 2);
    const int rw = (w < 248) ? 0 : ((w < 256 - SHIFT) ? 1 : 2);
    mycode = rh * 3 + rw;
  }
  const int hs = (h + SHIFT) & 255;
  const int wsm = (w + SHIFT) & 255;
  const long tok = ((long)b * 256 + hs) * 256 + wsm;
  const ushort* qb = qkv + tok * 768 + head * 32;
  float q[32];
  #pragma unroll
  for (int d2 = 0; d2 < 16; ++d2){
    const uint u = *(const uint*)(qb + d2 * 2);
    q[d2 * 2]     = bflo(u) * SCALE;
    q[d2 * 2 + 1] = bfhi(u) * SCALE;
  }
  __syncthreads();

  const int hb = wid * 32;
  f32x4v o[8];
  #pragma unroll
  for (int d4 = 0; d4 < 8; ++d4) o[d4] = (f32x4v){0.f, 0.f, 0.f, 0.f};
  float sum = 0.f;
  for (int k = 0; k < 64; ++k){
    float s0 = 0.f, s1 = 0.f, s2 = 0.f, s3 = 0.f;
    #pragma unroll
    for (int d4 = 0; d4 < 8; ++d4){
      const f32x4v kv = *(const f32x4v*)&Kf[k][hb + d4 * 4];
      s0 += q[d4 * 4 + 0] * kv[0];
      s1 += q[d4 * 4 + 1] * kv[1];
      s2 += q[d4 * 4 + 2] * kv[2];
      s3 += q[d4 * 4 + 3] * kv[3];
    }
    float s = (s0 + s1) + (s2 + s3);
    s += bias_s[wid][(th - (k >> 3) + 7) * 15 + (tw - (k & 7) + 7)];
    if (SHIFT > 0 && mycode != code_s[k]) s -= 100.f;
    const float p = __expf(s);
    sum += p;
    #pragma unroll
    for (int d4 = 0; d4 < 8; ++d4){
      const f32x4v vv = *(const f32x4v*)&Vf[k][hb + d4 * 4];
      o[d4] += p * vv;
    }
  }
  const float inv = 1.f / sum;
  ushort* ob = outp + tok * 256 + head * 32;
  #pragma unroll
  for (int d4 = 0; d4 < 8; ++d4){
    ushort4 ov = { f2bf(o[d4][0] * inv), f2bf(o[d4][1] * inv),
                   f2bf(o[d4][2] * inv), f2bf(o[d4][3] * inv) };
    *(ushort4*)(ob + d4 * 4) = ov;
  }
}

extern "C" void kernel_launch(void* const* d_in, const int* in_sizes, int n_in,
                              void* d_out, int out_size, void* d_ws, size_t ws_size,
                              hipStream_t stream){
  const float* pcd    = (const float*)d_in[0];
  const float* img    = (const float*)d_in[1];
  const float* rd_w1  = (const float*)d_in[2];
  const float* rd_b1  = (const float*)d_in[3];
  const float* rd_lng = (const float*)d_in[4];
  const float* rd_lnb = (const float*)d_in[5];
  const float* rd_w2  = (const float*)d_in[6];
  const float* rd_b2  = (const float*)d_in[7];
  const float* n1g    = (const float*)d_in[8];
  const float* n1b    = (const float*)d_in[9];
  const float* qkv_w  = (const float*)d_in[10];
  const float* qkv_b  = (const float*)d_in[11];
  const float* rpb    = (const float*)d_in[12];
  const float* proj_w = (const float*)d_in[13];
  const float* proj_b = (const float*)d_in[14];
  const float* n2g    = (const float*)d_in[15];
  const float* n2b    = (const float*)d_in[16];
  const float* mlp_w1 = (const float*)d_in[17];
  const float* mlp_b1 = (const float*)d_in[18];
  const float* mlp_w2 = (const float*)d_in[19];
  const float* mlp_b2 = (const float*)d_in[20];

  char* ws = (char*)d_ws;
  ushort* w1b    = (ushort*)(ws + 0);                // 2048x512 bf16   2 MB
  ushort* w2g    = (ushort*)(ws + 2097152);          // 256x2048 (γ·w)  1 MB
  ushort* qkvwg  = (ushort*)(ws + 3145728);          // 2x768x256 (γ·w) 0.75 MB
  ushort* projwb = (ushort*)(ws + 3932160);          // 2x256x256       0.25 MB
  ushort* mlp1wg = (ushort*)(ws + 4194304);          // 2x1024x256 (γ·w) 1 MB
  ushort* mlp2wb = (ushort*)(ws + 5242880);          // 2x256x1024      1 MB
  float*  cvec   = (float*)(ws + 6291456);           // 32 KB c1/c2 pool
  float*  w2c1   = cvec,        *w2c2   = cvec + 256;
  float*  qkvc1  = cvec + 512,  *qkvc2  = cvec + 2048;   // 2x768 each
  float*  mlp1c1 = cvec + 3584, *mlp1c2 = cvec + 5632;   // 2x1024 each
  float*  stats  = (float*)(ws + 6324224);           // T x 2 f32  1 MB
  ushort* xr     = (ushort*)(ws + 7372800);          // residual, T x 256 bf16  67 MB
  char*   big    = ws + 74481664;                    // 268,435,456 B region
  ushort* A0     = (ushort*)big;                     // T x 512 bf16 (134 MB)
  ushort* X1c    = (ushort*)(big + 134217728);       // 32768 x 2048 (134 MB)
  ushort* qkvb   = (ushort*)big;                     // T x 768 (201 MB)
  ushort* attno  = (ushort*)(big + 201326592);       // T x 256 (67 MB)
  ushort* hidden = (ushort*)big;                     // T x 1024 (268 MB)
  float* xout = (float*)d_out;                       // final output f32
  // peak ws use = 74,481,664 + 268,435,456 = 342,917,120 B

  // ---- weight preprocessing ----
  cvtw_k<<<1024, 256, 0, stream>>>(rd_w1, w1b, 262144);
  cvtw_k<<<128,  256, 0, stream>>>(proj_w, projwb, 32768);
  cvtw_k<<<512,  256, 0, stream>>>(mlp_w2, mlp2wb, 131072);
  cvtwg_k<<<256, 64, 0, stream>>>(rd_w2, rd_lng, rd_lnb, w2g, w2c1, w2c2, 2048);
  for (int i = 0; i < 2; ++i){
    cvtwg_k<<<768, 64, 0, stream>>>(qkv_w + i * 196608, n1g + i * 256, n1b + i * 256,
        qkvwg + i * 196608, qkvc1 + i * 768, qkvc2 + i * 768, 256);
    cvtwg_k<<<1024, 64, 0, stream>>>(mlp_w1 + i * 262144, n2g + i * 256, n2b + i * 256,
        mlp1wg + i * 262144, mlp1c1 + i * 1024, mlp1c2 + i * 1024, 256);
  }
  concat_k<<<65536, 256, 0, stream>>>(pcd, img, A0);

  // ---- reduce block, chunked over M ----
  for (int c = 0; c < 4; ++c){
    const long off = (long)c * MCHUNK;
    gemm_k<1,1,0,false><<<4096, 256, 0, stream>>>(A0 + off * 512, w1b, rd_b1,
        nullptr, X1c, nullptr, nullptr, nullptr, nullptr, nullptr, 2048, 512, 16);
    rowstats_k<<<MCHUNK, 256, 0, stream>>>(X1c, stats + off * 2);
    gemm_k<0,1,0,true><<<512, 256, 0, stream>>>(X1c, w2g, rd_b2,
        nullptr, xr + off * 256, nullptr, nullptr,
        stats + off * 2, w2c1, w2c2, 256, 2048, 2);
  }
  stats256b_k<<<TOK / 4, 256, 0, stream>>>(xr, stats);

  // ---- Swin layers ----
  for (int i = 0; i < 2; ++i){
    gemm_k<0,1,0,true><<<6144, 256, 0, stream>>>(xr, qkvwg + i * 196608, qkv_b + i * 768,
        nullptr, qkvb, nullptr, nullptr, stats, qkvc1 + i * 768, qkvc2 + i * 768,
        768, 256, 6);
    if (i == 0)
      attn_k<0><<<4096, 256, 0, stream>>>(qkvb, rpb, attno);
    else
      attn_k<4><<<4096, 256, 0, stream>>>(qkvb, rpb + 1800, attno);
    gemm_k<0,1,1,false><<<2048, 256, 0, stream>>>(attno, projwb + i * 65536,
        proj_b + i * 256, nullptr, xr, xr, nullptr, nullptr, nullptr, nullptr, 256, 256, 2);
    stats256b_k<<<TOK / 4, 256, 0, stream>>>(xr, stats);
    gemm_k<2,1,0,true><<<8192, 256, 0, stream>>>(xr, mlp1wg + i * 262144,
        mlp_b1 + i * 1024, nullptr, hidden, nullptr, nullptr,
        stats, mlp1c1 + i * 1024, mlp1c2 + i * 1024, 1024, 256, 8);
    if (i == 0){
      gemm_k<0,1,1,false><<<2048, 256, 0, stream>>>(hidden, mlp2wb, mlp_b2,
          nullptr, xr, xr, nullptr, nullptr, nullptr, nullptr, 256, 1024, 2);
      stats256b_k<<<TOK / 4, 256, 0, stream>>>(xr, stats);
    } else {
      gemm_k<0,0,2,false><<<2048, 256, 0, stream>>>(hidden, mlp2wb + 262144,
          mlp_b2 + 256, xout, nullptr, xr, pcd, nullptr, nullptr, nullptr, 256, 1024, 2);
    }
  }
}

// Round 14
// 2112.159 us; speedup vs baseline: 2.5517x; 1.0571x over previous
//
#include <hip/hip_runtime.h>
#include <math.h>

typedef __attribute__((ext_vector_type(4))) float f32x4v;
typedef __attribute__((ext_vector_type(8))) __bf16 bf16x8v;
typedef __attribute__((ext_vector_type(2))) uint u32x2v;
typedef __attribute__((ext_vector_type(4))) uint u32x4v;

#define SCALE 0.17677669529663687f
#define TOK 131072
#define MCHUNK 32768

__device__ __forceinline__ ushort f2bf(float v){
  uint x = __float_as_uint(v);
  return (ushort)((x + 0x7fffu + ((x >> 16) & 1u)) >> 16);
}
__device__ __forceinline__ float bflo(uint u){ return __uint_as_float(u << 16); }
__device__ __forceinline__ float bfhi(uint u){ return __uint_as_float(u & 0xffff0000u); }
__device__ __forceinline__ float bf2f(ushort u){ return __uint_as_float((uint)u << 16); }

// ---- async global->LDS, 16B per lane. lds dest = wave-uniform base + lane*16.
__device__ __forceinline__ void gload16(const void* g, void* l){
  __builtin_amdgcn_global_load_lds(
      (const __attribute__((address_space(1))) uint*)g,
      (__attribute__((address_space(3))) uint*)l, 16, 0, 0);
}

// ---------------- weight f32 -> bf16 convert ----------------
__global__ __launch_bounds__(256) void cvtw_k(const float* __restrict__ src,
    ushort* __restrict__ dst, int n4){
  const int i = blockIdx.x * 256 + threadIdx.x;
  if (i >= n4) return;
  float4 v = ((const float4*)src)[i];
  ushort4 o = { f2bf(v.x), f2bf(v.y), f2bf(v.z), f2bf(v.w) };
  ((ushort4*)dst)[i] = o;
}

// ---- gamma-folded weight convert + c1=sum(gamma*w), c2=sum(beta*w). one wave/row ----
__global__ __launch_bounds__(64) void cvtwg_k(const float* __restrict__ src,
    const float* __restrict__ gma, const float* __restrict__ bta,
    ushort* __restrict__ dst, float* __restrict__ c1, float* __restrict__ c2, int K){
  const int n = blockIdx.x, lane = threadIdx.x;
  const float* sp = src + (long)n * K;
  ushort* dp = dst + (long)n * K;
  float s1 = 0.f, s2 = 0.f;
  for (int k = lane * 4; k < K; k += 256){
    float4 wv = *(const float4*)(sp + k);
    float4 gv = *(const float4*)(gma + k);
    float4 bv = *(const float4*)(bta + k);
    s1 += wv.x * gv.x + wv.y * gv.y + wv.z * gv.z + wv.w * gv.w;
    s2 += wv.x * bv.x + wv.y * bv.y + wv.z * bv.z + wv.w * bv.w;
    ushort4 o = { f2bf(wv.x * gv.x), f2bf(wv.y * gv.y), f2bf(wv.z * gv.z), f2bf(wv.w * gv.w) };
    *(ushort4*)(dp + k) = o;
  }
  #pragma unroll
  for (int o = 1; o < 64; o <<= 1){ s1 += __shfl_xor(s1, o); s2 += __shfl_xor(s2, o); }
  if (lane == 0){ c1[n] = s1; c2[n] = s2; }
}

// ---------------- concat pcd|img -> bf16 A0 [T][512] ----------------
__global__ __launch_bounds__(256) void concat_k(const float* __restrict__ pcd,
    const float* __restrict__ img, ushort* __restrict__ A0){
  const long gid = (long)blockIdx.x * 256 + threadIdx.x;  // over T*512/4
  const long t = gid >> 7;
  const int c4 = (int)(gid & 127) * 4;
  const float* src = (c4 < 256) ? (pcd + t * 256 + c4) : (img + t * 256 + (c4 - 256));
  float4 v = *(const float4*)src;
  ushort4 o = { f2bf(v.x), f2bf(v.y), f2bf(v.z), f2bf(v.w) };
  __builtin_nontemporal_store(*(u32x2v*)&o, (u32x2v*)(A0 + t * 512 + c4));
}

// ---------------- row stats over X1 chunk [rows][2048] bf16 -> (mean,rstd) ----------------
__global__ __launch_bounds__(256) void rowstats_k(const ushort* __restrict__ X,
    float* __restrict__ stats){
  const int row = blockIdx.x, tid = threadIdx.x;
  uint4 u = *(const uint4*)(X + (long)row * 2048 + tid * 8);
  float s = 0.f, q = 0.f;
  uint* e = (uint*)&u;
  #pragma unroll
  for (int c = 0; c < 4; ++c){
    float a = bflo(e[c]), b2 = bfhi(e[c]);
    s += a + b2; q += a * a + b2 * b2;
  }
  #pragma unroll
  for (int o = 1; o < 64; o <<= 1){ s += __shfl_xor(s, o); q += __shfl_xor(q, o); }
  __shared__ float ss[4], qs[4];
  if ((tid & 63) == 0){ ss[tid >> 6] = s; qs[tid >> 6] = q; }
  __syncthreads();
  if (tid == 0){
    float S = ss[0] + ss[1] + ss[2] + ss[3];
    float Q = qs[0] + qs[1] + qs[2] + qs[3];
    float mean = S * (1.f / 2048.f);
    float var = Q * (1.f / 2048.f) - mean * mean;
    stats[row * 2] = mean;
    stats[row * 2 + 1] = rsqrtf(var + 1e-5f);
  }
}

// ---------------- row stats over xr bf16 [T][256] -> (mean,rstd) ----------------
__global__ __launch_bounds__(256) void stats256b_k(const ushort* __restrict__ xb,
    float* __restrict__ stats){
  const int lane = threadIdx.x & 63, wd = threadIdx.x >> 6;
  const long row = (long)blockIdx.x * 4 + wd;
  uint2 u = *(const uint2*)(xb + row * 256 + lane * 4);
  float a = bflo(u.x), b2 = bfhi(u.x), c = bflo(u.y), d = bfhi(u.y);
  float s = a + b2 + c + d;
  float q = a * a + b2 * b2 + c * c + d * d;
  #pragma unroll
  for (int o = 1; o < 64; o <<= 1){ s += __shfl_xor(s, o); q += __shfl_xor(q, o); }
  if (lane == 0){
    float mean = s * (1.f / 256.f);
    float var = q * (1.f / 256.f) - mean * mean;
    stats[row * 2] = mean;
    stats[row * 2 + 1] = rsqrtf(var + 1e-5f);
  }
}

// ---------------- bf16 MFMA GEMM: record config + NT stores + occupancy param ----------------
// C[M,N] = epi(A[M,K] @ W[N,K]^T). ACT: 0 none,1 leaky,2 gelu(tanh). OUTT: 0 f32,1 bf16.
// RES: 0 none,1 +res(bf16),2 +res(bf16)+pcd(f32).
// LNEPI: v = rs*acc - mu*rs*c1[n] + c2[n] (then +bias). MINB: min blocks/CU.
template<int ACT, int OUTT, int RES, bool LNEPI, int MINB>
__global__ __launch_bounds__(256, MINB) void gemm_k(
    const ushort* __restrict__ A, const ushort* __restrict__ W,
    const float* __restrict__ bias,
    float* __restrict__ outf, ushort* __restrict__ outb,
    const ushort* __restrict__ res, const float* __restrict__ pcdp,
    const float* __restrict__ stats, const float* __restrict__ c1v,
    const float* __restrict__ c2v, int N, int K, int gx)
{
  __shared__ ushort As[2][128 * 32];
  __shared__ ushort Bs[2][128 * 32];
  const int tid = threadIdx.x;
  const int lane = tid & 63, w = tid >> 6;
  const int nwg = gridDim.x;
  int bid = blockIdx.x;
  bid = (bid & 7) * (nwg >> 3) + (bid >> 3);   // XCD-aware, m-major per XCD
  const int mBase = (bid / gx) * 128;
  const int nBase = (bid % gx) * 128;
  const int fr = lane & 15, grp = lane >> 4;
  const int wr = w >> 1, wc = w & 1;

  f32x4v acc[4][4];
  #pragma unroll
  for (int i = 0; i < 4; ++i)
    #pragma unroll
    for (int j = 0; j < 4; ++j) acc[i][j] = (f32x4v){0.f, 0.f, 0.f, 0.f};

  const ushort* Ap = A + (long)(mBase + w * 32 + (lane >> 2)) * K + (lane & 3) * 8;
  const ushort* Wp = W + (long)(nBase + w * 32 + (lane >> 2)) * K + (lane & 3) * 8;
  const long rowstep = (long)16 * K;
  const int woff = (w * 32) * 32;

  // prologue: stage tile 0 into buf 0
  gload16(Ap, &As[0][woff]);
  gload16(Ap + rowstep, &As[0][woff + 512]);
  gload16(Wp, &Bs[0][woff]);
  gload16(Wp + rowstep, &Bs[0][woff + 512]);
  Ap += 32; Wp += 32;
  __syncthreads();

  int cur = 0;
  for (int kt = 0; kt < K; kt += 32){
    if (kt + 32 < K){
      const int nxt = cur ^ 1;
      gload16(Ap, &As[nxt][woff]);
      gload16(Ap + rowstep, &As[nxt][woff + 512]);
      gload16(Wp, &Bs[nxt][woff]);
      gload16(Wp + rowstep, &Bs[nxt][woff + 512]);
      Ap += 32; Wp += 32;
    }
    bf16x8v af[4], bv[4];
    #pragma unroll
    for (int i = 0; i < 4; ++i)
      af[i] = *(const bf16x8v*)&As[cur][(wr * 64 + i * 16 + fr) * 32 + grp * 8];
    #pragma unroll
    for (int j = 0; j < 4; ++j)
      bv[j] = *(const bf16x8v*)&Bs[cur][(wc * 64 + j * 16 + fr) * 32 + grp * 8];
    #pragma unroll
    for (int i = 0; i < 4; ++i)
      #pragma unroll
      for (int j = 0; j < 4; ++j)
        acc[i][j] = __builtin_amdgcn_mfma_f32_16x16x32_bf16(af[i], bv[j], acc[i][j], 0, 0, 0);
    __syncthreads();   // drains next-tile loads; frees cur for restaging
    cur ^= 1;
  }

  // ---- epilogue ----
  float muv[16], rsv[16];
  if (LNEPI){
    #pragma unroll
    for (int i = 0; i < 4; ++i)
      #pragma unroll
      for (int rr = 0; rr < 4; ++rr){
        const int m = mBase + wr * 64 + i * 16 + grp * 4 + rr;
        muv[i * 4 + rr] = stats[m * 2];
        rsv[i * 4 + rr] = stats[m * 2 + 1];
      }
  }
  #pragma unroll
  for (int j = 0; j < 4; ++j){
    const int n = nBase + wc * 64 + j * 16 + fr;
    const float bn = bias[n];
    float c1n = 0.f, c2n = 0.f;
    if (LNEPI){ c1n = c1v[n]; c2n = c2v[n]; }
    #pragma unroll
    for (int i = 0; i < 4; ++i){
      #pragma unroll
      for (int rr = 0; rr < 4; ++rr){
        const long m = mBase + wr * 64 + i * 16 + grp * 4 + rr;
        float v = acc[i][j][rr];
        if (LNEPI) v = rsv[i * 4 + rr] * v - muv[i * 4 + rr] * rsv[i * 4 + rr] * c1n + c2n;
        v += bn;
        if (ACT == 1) v = v > 0.f ? v : 0.01f * v;
        if (ACT == 2){
          // tanh-form GELU via hw exp: max |err| vs exact erf ~5e-4 (<< bf16 rounding)
          const float u = v * (0.7978845608f + 0.0356774081f * v * v);
          const float t = 1.f - 2.f / (__expf(2.f * u) + 1.f);
          v = 0.5f * v * (1.f + t);
        }
        if (RES >= 1) v += bf2f(res[m * N + n]);
        if (RES == 2) v += pcdp[m * N + n];
        acc[i][j][rr] = v;
        if (OUTT == 0) __builtin_nontemporal_store(v, &outf[m * N + n]);
      }
    }
  }
  // ---- bf16 output: LDS-staged, 16B coalesced nontemporal stores ----
  if (OUTT == 1){
    ushort* eb = &As[0][0];   // 16 KB = 64 x 128 bf16
    __syncthreads();
    #pragma unroll
    for (int p = 0; p < 2; ++p){
      if (wr == p){
        #pragma unroll
        for (int i = 0; i < 4; ++i)
          #pragma unroll
          for (int rr = 0; rr < 4; ++rr){
            const int rl = i * 16 + grp * 4 + rr;
            #pragma unroll
            for (int j = 0; j < 4; ++j)
              eb[rl * 128 + wc * 64 + j * 16 + fr] = f2bf(acc[i][j][rr]);
          }
      }
      __syncthreads();
      #pragma unroll
      for (int it = 0; it < 4; ++it){
        const int c = it * 256 + tid;           // 1024 chunks of 16B
        const int row = c >> 4, col = (c & 15) * 8;
        const u32x4v val = *(const u32x4v*)&eb[row * 128 + col];
        __builtin_nontemporal_store(val,
            (u32x4v*)(outb + (long)(mBase + p * 64 + row) * N + nBase + col));
      }
      __syncthreads();
    }
  }
}

// ---------------- window attention: one block = (window, 4-head group), 4 waves ----------------
template<int SHIFT>
__global__ __launch_bounds__(256) void attn_k(const ushort* __restrict__ qkv,
    const float* __restrict__ rpb, ushort* __restrict__ outp)
{
  __shared__ float Kf[64][132];   // [token][4 heads x 32d], pad 4
  __shared__ float Vf[64][132];
  __shared__ float bias_s[4][226];
  __shared__ int code_s[64];
  const int tid = threadIdx.x;
  const int lane = tid & 63, wid = tid >> 6;
  const int hg = blockIdx.x & 1;
  const int bw = blockIdx.x >> 1;           // window id
  const int b = bw >> 10, widx = bw & 1023;
  const int wh = widx >> 5, ww = widx & 31;
  const int head = hg * 4 + wid;

  for (int i = lane; i < 225; i += 64) bias_s[wid][i] = rpb[i * 8 + head];

  if (SHIFT > 0 && tid < 64){
    const int hh = wh * 8 + (tid >> 3), wwp = ww * 8 + (tid & 7);
    const int rh = (hh < 248) ? 0 : ((hh < 256 - SHIFT) ? 1 : 2);
    const int rw = (wwp < 248) ? 0 : ((wwp < 256 - SHIFT) ? 1 : 2);
    code_s[tid] = rh * 3 + rw;
  }

  #pragma unroll
  for (int it = 0; it < 4; ++it){
    const int c = it * 256 + tid;             // 1024 chunks over [64 rows][16 parts]
    const int row = c >> 4, part = c & 15;
    const int hs = (wh * 8 + (row >> 3) + SHIFT) & 255;
    const int wsm = (ww * 8 + (row & 7) + SHIFT) & 255;
    const long tk = ((long)b * 256 + hs) * 256 + wsm;
    const uint4 ku = *(const uint4*)(qkv + tk * 768 + 256 + hg * 128 + part * 8);
    const uint4 vu = *(const uint4*)(qkv + tk * 768 + 512 + hg * 128 + part * 8);
    const uint* ke = (const uint*)&ku;
    const uint* ve = (const uint*)&vu;
    #pragma unroll
    for (int e = 0; e < 4; ++e){
      Kf[row][part * 8 + e * 2]     = bflo(ke[e]);
      Kf[row][part * 8 + e * 2 + 1] = bfhi(ke[e]);
      Vf[row][part * 8 + e * 2]     = bflo(ve[e]);
      Vf[row][part * 8 + e * 2 + 1] = bfhi(ve[e]);
    }
  }

  const int th = lane >> 3, tw = lane & 7;
  const int h = wh * 8 + th, w = ww * 8 + tw;
  int mycode = 0;
  if (SHIFT > 0){
    const int rh = (h < 248) ? 0 : ((h < 256 - SHIFT) ? 1 : 2);
    const int rw = (w < 248) ? 0 : ((w < 256 - SHIFT) ? 1 : 2);
    mycode = rh * 3 + rw;
  }
  const int hs = (h + SHIFT) & 255;
  const int wsm = (w + SHIFT) & 255;
  const long tok = ((long)b * 256 + hs) * 256 + wsm;
  const ushort* qb = qkv + tok * 768 + head * 32;
  float q[32];
  #pragma unroll
  for (int d2 = 0; d2 < 16; ++d2){
    const uint u = *(const uint*)(qb + d2 * 2);
    q[d2 * 2]     = bflo(u) * SCALE;
    q[d2 * 2 + 1] = bfhi(u) * SCALE;
  }
  __syncthreads();

  const int hb = wid * 32;
  f32x4v o[8];
  #pragma unroll
  for (int d4 = 0; d4 < 8; ++d4) o[d4] = (f32x4v){0.f, 0.f, 0.f, 0.f};
  float sum = 0.f;
  for (int k = 0; k < 64; ++k){
    float s0 = 0.f, s1 = 0.f, s2 = 0.f, s3 = 0.f;
    #pragma unroll
    for (int d4 = 0; d4 < 8; ++d4){
      const f32x4v kv = *(const f32x4v*)&Kf[k][hb + d4 * 4];
      s0 += q[d4 * 4 + 0] * kv[0];
      s1 += q[d4 * 4 + 1] * kv[1];
      s2 += q[d4 * 4 + 2] * kv[2];
      s3 += q[d4 * 4 + 3] * kv[3];
    }
    float s = (s0 + s1) + (s2 + s3);
    s += bias_s[wid][(th - (k >> 3) + 7) * 15 + (tw - (k & 7) + 7)];
    if (SHIFT > 0 && mycode != code_s[k]) s -= 100.f;
    const float p = __expf(s);
    sum += p;
    #pragma unroll
    for (int d4 = 0; d4 < 8; ++d4){
      const f32x4v vv = *(const f32x4v*)&Vf[k][hb + d4 * 4];
      o[d4] += p * vv;
    }
  }
  const float inv = 1.f / sum;
  ushort* ob = outp + tok * 256 + head * 32;
  #pragma unroll
  for (int d4 = 0; d4 < 8; ++d4){
    ushort4 ov = { f2bf(o[d4][0] * inv), f2bf(o[d4][1] * inv),
                   f2bf(o[d4][2] * inv), f2bf(o[d4][3] * inv) };
    *(ushort4*)(ob + d4 * 4) = ov;
  }
}

extern "C" void kernel_launch(void* const* d_in, const int* in_sizes, int n_in,
                              void* d_out, int out_size, void* d_ws, size_t ws_size,
                              hipStream_t stream){
  const float* pcd    = (const float*)d_in[0];
  const float* img    = (const float*)d_in[1];
  const float* rd_w1  = (const float*)d_in[2];
  const float* rd_b1  = (const float*)d_in[3];
  const float* rd_lng = (const float*)d_in[4];
  const float* rd_lnb = (const float*)d_in[5];
  const float* rd_w2  = (const float*)d_in[6];
  const float* rd_b2  = (const float*)d_in[7];
  const float* n1g    = (const float*)d_in[8];
  const float* n1b    = (const float*)d_in[9];
  const float* qkv_w  = (const float*)d_in[10];
  const float* qkv_b  = (const float*)d_in[11];
  const float* rpb    = (const float*)d_in[12];
  const float* proj_w = (const float*)d_in[13];
  const float* proj_b = (const float*)d_in[14];
  const float* n2g    = (const float*)d_in[15];
  const float* n2b    = (const float*)d_in[16];
  const float* mlp_w1 = (const float*)d_in[17];
  const float* mlp_b1 = (const float*)d_in[18];
  const float* mlp_w2 = (const float*)d_in[19];
  const float* mlp_b2 = (const float*)d_in[20];

  char* ws = (char*)d_ws;
  ushort* w1b    = (ushort*)(ws + 0);                // 2048x512 bf16   2 MB
  ushort* w2g    = (ushort*)(ws + 2097152);          // 256x2048 (γ·w)  1 MB
  ushort* qkvwg  = (ushort*)(ws + 3145728);          // 2x768x256 (γ·w) 0.75 MB
  ushort* projwb = (ushort*)(ws + 3932160);          // 2x256x256       0.25 MB
  ushort* mlp1wg = (ushort*)(ws + 4194304);          // 2x1024x256 (γ·w) 1 MB
  ushort* mlp2wb = (ushort*)(ws + 5242880);          // 2x256x1024      1 MB
  float*  cvec   = (float*)(ws + 6291456);           // 32 KB c1/c2 pool
  float*  w2c1   = cvec,        *w2c2   = cvec + 256;
  float*  qkvc1  = cvec + 512,  *qkvc2  = cvec + 2048;   // 2x768 each
  float*  mlp1c1 = cvec + 3584, *mlp1c2 = cvec + 5632;   // 2x1024 each
  float*  stats  = (float*)(ws + 6324224);           // T x 2 f32  1 MB
  ushort* xr     = (ushort*)(ws + 7372800);          // residual, T x 256 bf16  67 MB
  char*   big    = ws + 74481664;                    // 268,435,456 B region
  ushort* A0     = (ushort*)big;                     // T x 512 bf16 (134 MB)
  ushort* X1c    = (ushort*)(big + 134217728);       // 32768 x 2048 (134 MB)
  ushort* qkvb   = (ushort*)big;                     // T x 768 (201 MB)
  ushort* attno  = (ushort*)(big + 201326592);       // T x 256 (67 MB)
  ushort* hidden = (ushort*)big;                     // T x 1024 (268 MB)
  float* xout = (float*)d_out;                       // final output f32
  // peak ws use = 74,481,664 + 268,435,456 = 342,917,120 B

  // ---- weight preprocessing ----
  cvtw_k<<<1024, 256, 0, stream>>>(rd_w1, w1b, 262144);
  cvtw_k<<<128,  256, 0, stream>>>(proj_w, projwb, 32768);
  cvtw_k<<<512,  256, 0, stream>>>(mlp_w2, mlp2wb, 131072);
  cvtwg_k<<<256, 64, 0, stream>>>(rd_w2, rd_lng, rd_lnb, w2g, w2c1, w2c2, 2048);
  for (int i = 0; i < 2; ++i){
    cvtwg_k<<<768, 64, 0, stream>>>(qkv_w + i * 196608, n1g + i * 256, n1b + i * 256,
        qkvwg + i * 196608, qkvc1 + i * 768, qkvc2 + i * 768, 256);
    cvtwg_k<<<1024, 64, 0, stream>>>(mlp_w1 + i * 262144, n2g + i * 256, n2b + i * 256,
        mlp1wg + i * 262144, mlp1c1 + i * 1024, mlp1c2 + i * 1024, 256);
  }
  concat_k<<<65536, 256, 0, stream>>>(pcd, img, A0);

  // ---- reduce block, chunked over M ----
  for (int c = 0; c < 4; ++c){
    const long off = (long)c * MCHUNK;
    gemm_k<1,1,0,false,4><<<4096, 256, 0, stream>>>(A0 + off * 512, w1b, rd_b1,
        nullptr, X1c, nullptr, nullptr, nullptr, nullptr, nullptr, 2048, 512, 16);
    rowstats_k<<<MCHUNK, 256, 0, stream>>>(X1c, stats + off * 2);
    gemm_k<0,1,0,true,3><<<512, 256, 0, stream>>>(X1c, w2g, rd_b2,
        nullptr, xr + off * 256, nullptr, nullptr,
        stats + off * 2, w2c1, w2c2, 256, 2048, 2);
  }
  stats256b_k<<<TOK / 4, 256, 0, stream>>>(xr, stats);

  // ---- Swin layers ----
  for (int i = 0; i < 2; ++i){
    gemm_k<0,1,0,true,3><<<6144, 256, 0, stream>>>(xr, qkvwg + i * 196608, qkv_b + i * 768,
        nullptr, qkvb, nullptr, nullptr, stats, qkvc1 + i * 768, qkvc2 + i * 768,
        768, 256, 6);
    if (i == 0)
      attn_k<0><<<4096, 256, 0, stream>>>(qkvb, rpb, attno);
    else
      attn_k<4><<<4096, 256, 0, stream>>>(qkvb, rpb + 1800, attno);
    gemm_k<0,1,1,false,3><<<2048, 256, 0, stream>>>(attno, projwb + i * 65536,
        proj_b + i * 256, nullptr, xr, xr, nullptr, nullptr, nullptr, nullptr, 256, 256, 2);
    stats256b_k<<<TOK / 4, 256, 0, stream>>>(xr, stats);
    gemm_k<2,1,0,true,3><<<8192, 256, 0, stream>>>(xr, mlp1wg + i * 262144,
        mlp_b1 + i * 1024, nullptr, hidden, nullptr, nullptr,
        stats, mlp1c1 + i * 1024, mlp1c2 + i * 1024, 1024, 256, 8);
    if (i == 0){
      gemm_k<0,1,1,false,3><<<2048, 256, 0, stream>>>(hidden, mlp2wb, mlp_b2,
          nullptr, xr, xr, nullptr, nullptr, nullptr, nullptr, 256, 1024, 2);
      stats256b_k<<<TOK / 4, 256, 0, stream>>>(xr, stats);
    } else {
      gemm_k<0,0,2,false,3><<<2048, 256, 0, stream>>>(hidden, mlp2wb + 262144,
          mlp_b2 + 256, xout, nullptr, xr, pcd, nullptr, nullptr, nullptr, 256, 1024, 2);
    }
  }
}

// Round 15
// 2102.287 us; speedup vs baseline: 2.5637x; 1.0047x over previous
//
#include <hip/hip_runtime.h>
#include <math.h>

typedef __attribute__((ext_vector_type(4))) float f32x4v;
typedef __attribute__((ext_vector_type(8))) __bf16 bf16x8v;
typedef __attribute__((ext_vector_type(2))) uint u32x2v;
typedef __attribute__((ext_vector_type(4))) uint u32x4v;

#define SCALE 0.17677669529663687f
#define TOK 131072
#define MCHUNK 32768

__device__ __forceinline__ ushort f2bf(float v){
  uint x = __float_as_uint(v);
  return (ushort)((x + 0x7fffu + ((x >> 16) & 1u)) >> 16);
}
__device__ __forceinline__ float bflo(uint u){ return __uint_as_float(u << 16); }
__device__ __forceinline__ float bfhi(uint u){ return __uint_as_float(u & 0xffff0000u); }
__device__ __forceinline__ float bf2f(ushort u){ return __uint_as_float((uint)u << 16); }

// ---- async global->LDS, 16B per lane. lds dest = wave-uniform base + lane*16.
__device__ __forceinline__ void gload16(const void* g, void* l){
  __builtin_amdgcn_global_load_lds(
      (const __attribute__((address_space(1))) uint*)g,
      (__attribute__((address_space(3))) uint*)l, 16, 0, 0);
}

// ---------------- weight f32 -> bf16 convert ----------------
__global__ __launch_bounds__(256) void cvtw_k(const float* __restrict__ src,
    ushort* __restrict__ dst, int n4){
  const int i = blockIdx.x * 256 + threadIdx.x;
  if (i >= n4) return;
  float4 v = ((const float4*)src)[i];
  ushort4 o = { f2bf(v.x), f2bf(v.y), f2bf(v.z), f2bf(v.w) };
  ((ushort4*)dst)[i] = o;
}

// ---- gamma-folded weight convert + c1=sum(gamma*w), c2=sum(beta*w). one wave/row ----
__global__ __launch_bounds__(64) void cvtwg_k(const float* __restrict__ src,
    const float* __restrict__ gma, const float* __restrict__ bta,
    ushort* __restrict__ dst, float* __restrict__ c1, float* __restrict__ c2, int K){
  const int n = blockIdx.x, lane = threadIdx.x;
  const float* sp = src + (long)n * K;
  ushort* dp = dst + (long)n * K;
  float s1 = 0.f, s2 = 0.f;
  for (int k = lane * 4; k < K; k += 256){
    float4 wv = *(const float4*)(sp + k);
    float4 gv = *(const float4*)(gma + k);
    float4 bv = *(const float4*)(bta + k);
    s1 += wv.x * gv.x + wv.y * gv.y + wv.z * gv.z + wv.w * gv.w;
    s2 += wv.x * bv.x + wv.y * bv.y + wv.z * bv.z + wv.w * bv.w;
    ushort4 o = { f2bf(wv.x * gv.x), f2bf(wv.y * gv.y), f2bf(wv.z * gv.z), f2bf(wv.w * gv.w) };
    *(ushort4*)(dp + k) = o;
  }
  #pragma unroll
  for (int o = 1; o < 64; o <<= 1){ s1 += __shfl_xor(s1, o); s2 += __shfl_xor(s2, o); }
  if (lane == 0){ c1[n] = s1; c2[n] = s2; }
}

// ---------------- concat pcd|img -> bf16 A0 [T][512] ----------------
__global__ __launch_bounds__(256) void concat_k(const float* __restrict__ pcd,
    const float* __restrict__ img, ushort* __restrict__ A0){
  const long gid = (long)blockIdx.x * 256 + threadIdx.x;  // over T*512/4
  const long t = gid >> 7;
  const int c4 = (int)(gid & 127) * 4;
  const float* src = (c4 < 256) ? (pcd + t * 256 + c4) : (img + t * 256 + (c4 - 256));
  float4 v = *(const float4*)src;
  ushort4 o = { f2bf(v.x), f2bf(v.y), f2bf(v.z), f2bf(v.w) };
  __builtin_nontemporal_store(*(u32x2v*)&o, (u32x2v*)(A0 + t * 512 + c4));
}

// ---------------- row stats over X1 chunk [rows][2048] bf16 -> (mean,rstd) ----------------
__global__ __launch_bounds__(256) void rowstats_k(const ushort* __restrict__ X,
    float* __restrict__ stats){
  const int row = blockIdx.x, tid = threadIdx.x;
  uint4 u = *(const uint4*)(X + (long)row * 2048 + tid * 8);
  float s = 0.f, q = 0.f;
  uint* e = (uint*)&u;
  #pragma unroll
  for (int c = 0; c < 4; ++c){
    float a = bflo(e[c]), b2 = bfhi(e[c]);
    s += a + b2; q += a * a + b2 * b2;
  }
  #pragma unroll
  for (int o = 1; o < 64; o <<= 1){ s += __shfl_xor(s, o); q += __shfl_xor(q, o); }
  __shared__ float ss[4], qs[4];
  if ((tid & 63) == 0){ ss[tid >> 6] = s; qs[tid >> 6] = q; }
  __syncthreads();
  if (tid == 0){
    float S = ss[0] + ss[1] + ss[2] + ss[3];
    float Q = qs[0] + qs[1] + qs[2] + qs[3];
    float mean = S * (1.f / 2048.f);
    float var = Q * (1.f / 2048.f) - mean * mean;
    stats[row * 2] = mean;
    stats[row * 2 + 1] = rsqrtf(var + 1e-5f);
  }
}

// ---------------- row stats over xr bf16 [T][256] -> (mean,rstd) ----------------
__global__ __launch_bounds__(256) void stats256b_k(const ushort* __restrict__ xb,
    float* __restrict__ stats){
  const int lane = threadIdx.x & 63, wd = threadIdx.x >> 6;
  const long row = (long)blockIdx.x * 4 + wd;
  uint2 u = *(const uint2*)(xb + row * 256 + lane * 4);
  float a = bflo(u.x), b2 = bfhi(u.x), c = bflo(u.y), d = bfhi(u.y);
  float s = a + b2 + c + d;
  float q = a * a + b2 * b2 + c * c + d * d;
  #pragma unroll
  for (int o = 1; o < 64; o <<= 1){ s += __shfl_xor(s, o); q += __shfl_xor(q, o); }
  if (lane == 0){
    float mean = s * (1.f / 256.f);
    float var = q * (1.f / 256.f) - mean * mean;
    stats[row * 2] = mean;
    stats[row * 2 + 1] = rsqrtf(var + 1e-5f);
  }
}

// ---------------- bf16 MFMA GEMM: record config + 2D super-tile XCD traversal ----------------
// C[M,N] = epi(A[M,K] @ W[N,K]^T). ACT: 0 none,1 leaky,2 gelu(tanh). OUTT: 0 f32,1 bf16.
// RES: 0 none,1 +res(bf16),2 +res(bf16)+pcd(f32).
// LNEPI: v = rs*acc - mu*rs*c1[n] + c2[n] (then +bias). MINB: min blocks/CU.
template<int ACT, int OUTT, int RES, bool LNEPI, int MINB>
__global__ __launch_bounds__(256, MINB) void gemm_k(
    const ushort* __restrict__ A, const ushort* __restrict__ W,
    const float* __restrict__ bias,
    float* __restrict__ outf, ushort* __restrict__ outb,
    const ushort* __restrict__ res, const float* __restrict__ pcdp,
    const float* __restrict__ stats, const float* __restrict__ c1v,
    const float* __restrict__ c2v, int N, int K, int gx)
{
  __shared__ ushort As[2][128 * 32];
  __shared__ ushort Bs[2][128 * 32];
  const int tid = threadIdx.x;
  const int lane = tid & 63, w = tid >> 6;
  // XCD-aware 2D super-tile traversal: XCD owns a contiguous m-stripe; within it,
  // iterate super-tiles of 8 m-tiles x gx n-tiles, n-major inner (keeps B panel
  // AND an 8-m-tile A panel L2-resident; B fetched once per super-tile).
  const int nwg = gridDim.x;
  {
    const int xcd = blockIdx.x & 7;
    const int idx = blockIdx.x >> 3;          // [0, nwg/8)
    const int mPerX = nwg / (8 * gx);         // m-tiles per XCD (multiple of 8)
    const int sg = idx / (8 * gx);            // super-tile index
    const int u  = idx - sg * (8 * gx);
    const int nT = u >> 3;                    // n-tile (inner-major)
    const int ml = u & 7;                     // m within super-tile
    const int mT = xcd * mPerX + sg * 8 + ml;
    const int mBase = mT * 128;
    const int nBase = nT * 128;
    // fallthrough with mBase/nBase in scope via shadowing below
    const int fr = lane & 15, grp = lane >> 4;
    const int wr = w >> 1, wc = w & 1;

    f32x4v acc[4][4];
    #pragma unroll
    for (int i = 0; i < 4; ++i)
      #pragma unroll
      for (int j = 0; j < 4; ++j) acc[i][j] = (f32x4v){0.f, 0.f, 0.f, 0.f};

    const ushort* Ap = A + (long)(mBase + w * 32 + (lane >> 2)) * K + (lane & 3) * 8;
    const ushort* Wp = W + (long)(nBase + w * 32 + (lane >> 2)) * K + (lane & 3) * 8;
    const long rowstep = (long)16 * K;
    const int woff = (w * 32) * 32;

    // prologue: stage tile 0 into buf 0
    gload16(Ap, &As[0][woff]);
    gload16(Ap + rowstep, &As[0][woff + 512]);
    gload16(Wp, &Bs[0][woff]);
    gload16(Wp + rowstep, &Bs[0][woff + 512]);
    Ap += 32; Wp += 32;
    __syncthreads();

    int cur = 0;
    for (int kt = 0; kt < K; kt += 32){
      if (kt + 32 < K){
        const int nxt = cur ^ 1;
        gload16(Ap, &As[nxt][woff]);
        gload16(Ap + rowstep, &As[nxt][woff + 512]);
        gload16(Wp, &Bs[nxt][woff]);
        gload16(Wp + rowstep, &Bs[nxt][woff + 512]);
        Ap += 32; Wp += 32;
      }
      bf16x8v af[4], bv[4];
      #pragma unroll
      for (int i = 0; i < 4; ++i)
        af[i] = *(const bf16x8v*)&As[cur][(wr * 64 + i * 16 + fr) * 32 + grp * 8];
      #pragma unroll
      for (int j = 0; j < 4; ++j)
        bv[j] = *(const bf16x8v*)&Bs[cur][(wc * 64 + j * 16 + fr) * 32 + grp * 8];
      #pragma unroll
      for (int i = 0; i < 4; ++i)
        #pragma unroll
        for (int j = 0; j < 4; ++j)
          acc[i][j] = __builtin_amdgcn_mfma_f32_16x16x32_bf16(af[i], bv[j], acc[i][j], 0, 0, 0);
      __syncthreads();   // drains next-tile loads; frees cur for restaging
      cur ^= 1;
    }

    // ---- epilogue ----
    float muv[16], rsv[16];
    if (LNEPI){
      #pragma unroll
      for (int i = 0; i < 4; ++i)
        #pragma unroll
        for (int rr = 0; rr < 4; ++rr){
          const int m = mBase + wr * 64 + i * 16 + grp * 4 + rr;
          muv[i * 4 + rr] = stats[m * 2];
          rsv[i * 4 + rr] = stats[m * 2 + 1];
        }
    }
    #pragma unroll
    for (int j = 0; j < 4; ++j){
      const int n = nBase + wc * 64 + j * 16 + fr;
      const float bn = bias[n];
      float c1n = 0.f, c2n = 0.f;
      if (LNEPI){ c1n = c1v[n]; c2n = c2v[n]; }
      #pragma unroll
      for (int i = 0; i < 4; ++i){
        #pragma unroll
        for (int rr = 0; rr < 4; ++rr){
          const long m = mBase + wr * 64 + i * 16 + grp * 4 + rr;
          float v = acc[i][j][rr];
          if (LNEPI) v = rsv[i * 4 + rr] * v - muv[i * 4 + rr] * rsv[i * 4 + rr] * c1n + c2n;
          v += bn;
          if (ACT == 1) v = v > 0.f ? v : 0.01f * v;
          if (ACT == 2){
            // tanh-form GELU via hw exp: max |err| vs exact erf ~5e-4 (<< bf16 rounding)
            const float u2 = v * (0.7978845608f + 0.0356774081f * v * v);
            const float t = 1.f - 2.f / (__expf(2.f * u2) + 1.f);
            v = 0.5f * v * (1.f + t);
          }
          if (RES >= 1) v += bf2f(res[m * N + n]);
          if (RES == 2) v += pcdp[m * N + n];
          acc[i][j][rr] = v;
          if (OUTT == 0) __builtin_nontemporal_store(v, &outf[m * N + n]);
        }
      }
    }
    // ---- bf16 output: LDS-staged, 16B coalesced nontemporal stores ----
    if (OUTT == 1){
      ushort* eb = &As[0][0];   // 16 KB = 64 x 128 bf16
      __syncthreads();
      #pragma unroll
      for (int p = 0; p < 2; ++p){
        if (wr == p){
          #pragma unroll
          for (int i = 0; i < 4; ++i)
            #pragma unroll
            for (int rr = 0; rr < 4; ++rr){
              const int rl = i * 16 + grp * 4 + rr;
              #pragma unroll
              for (int j = 0; j < 4; ++j)
                eb[rl * 128 + wc * 64 + j * 16 + fr] = f2bf(acc[i][j][rr]);
            }
        }
        __syncthreads();
        #pragma unroll
        for (int it = 0; it < 4; ++it){
          const int c = it * 256 + tid;           // 1024 chunks of 16B
          const int row = c >> 4, col = (c & 15) * 8;
          const u32x4v val = *(const u32x4v*)&eb[row * 128 + col];
          __builtin_nontemporal_store(val,
              (u32x4v*)(outb + (long)(mBase + p * 64 + row) * N + nBase + col));
        }
        __syncthreads();
      }
    }
  }
}

// ---------------- window attention: one block = (window, 4-head group), 4 waves ----------------
template<int SHIFT>
__global__ __launch_bounds__(256) void attn_k(const ushort* __restrict__ qkv,
    const float* __restrict__ rpb, ushort* __restrict__ outp)
{
  __shared__ float Kf[64][132];   // [token][4 heads x 32d], pad 4
  __shared__ float Vf[64][132];
  __shared__ float bias_s[4][226];
  __shared__ int code_s[64];
  const int tid = threadIdx.x;
  const int lane = tid & 63, wid = tid >> 6;
  const int hg = blockIdx.x & 1;
  const int bw = blockIdx.x >> 1;           // window id
  const int b = bw >> 10, widx = bw & 1023;
  const int wh = widx >> 5, ww = widx & 31;
  const int head = hg * 4 + wid;

  for (int i = lane; i < 225; i += 64) bias_s[wid][i] = rpb[i * 8 + head];

  if (SHIFT > 0 && tid < 64){
    const int hh = wh * 8 + (tid >> 3), wwp = ww * 8 + (tid & 7);
    const int rh = (hh < 248) ? 0 : ((hh < 256 - SHIFT) ? 1 : 2);
    const int rw = (wwp < 248) ? 0 : ((wwp < 256 - SHIFT) ? 1 : 2);
    code_s[tid] = rh * 3 + rw;
  }

  #pragma unroll
  for (int it = 0; it < 4; ++it){
    const int c = it * 256 + tid;             // 1024 chunks over [64 rows][16 parts]
    const int row = c >> 4, part = c & 15;
    const int hs = (wh * 8 + (row >> 3) + SHIFT) & 255;
    const int wsm = (ww * 8 + (row & 7) + SHIFT) & 255;
    const long tk = ((long)b * 256 + hs) * 256 + wsm;
    const uint4 ku = *(const uint4*)(qkv + tk * 768 + 256 + hg * 128 + part * 8);
    const uint4 vu = *(const uint4*)(qkv + tk * 768 + 512 + hg * 128 + part * 8);
    const uint* ke = (const uint*)&ku;
    const uint* ve = (const uint*)&vu;
    #pragma unroll
    for (int e = 0; e < 4; ++e){
      Kf[row][part * 8 + e * 2]     = bflo(ke[e]);
      Kf[row][part * 8 + e * 2 + 1] = bfhi(ke[e]);
      Vf[row][part * 8 + e * 2]     = bflo(ve[e]);
      Vf[row][part * 8 + e * 2 + 1] = bfhi(ve[e]);
    }
  }

  const int th = lane >> 3, tw = lane & 7;
  const int h = wh * 8 + th, w = ww * 8 + tw;
  int mycode = 0;
  if (SHIFT > 0){
    const int rh = (h < 248) ? 0 : ((h < 256 - SHIFT) ? 1 : 2);
    const int rw = (w < 248) ? 0 : ((w < 256 - SHIFT) ? 1 : 2);
    mycode = rh * 3 + rw;
  }
  const int hs = (h + SHIFT) & 255;
  const int wsm = (w + SHIFT) & 255;
  const long tok = ((long)b * 256 + hs) * 256 + wsm;
  const ushort* qb = qkv + tok * 768 + head * 32;
  float q[32];
  #pragma unroll
  for (int d2 = 0; d2 < 16; ++d2){
    const uint u = *(const uint*)(qb + d2 * 2);
    q[d2 * 2]     = bflo(u) * SCALE;
    q[d2 * 2 + 1] = bfhi(u) * SCALE;
  }
  __syncthreads();

  const int hb = wid * 32;
  f32x4v o[8];
  #pragma unroll
  for (int d4 = 0; d4 < 8; ++d4) o[d4] = (f32x4v){0.f, 0.f, 0.f, 0.f};
  float sum = 0.f;
  for (int k = 0; k < 64; ++k){
    float s0 = 0.f, s1 = 0.f, s2 = 0.f, s3 = 0.f;
    #pragma unroll
    for (int d4 = 0; d4 < 8; ++d4){
      const f32x4v kv = *(const f32x4v*)&Kf[k][hb + d4 * 4];
      s0 += q[d4 * 4 + 0] * kv[0];
      s1 += q[d4 * 4 + 1] * kv[1];
      s2 += q[d4 * 4 + 2] * kv[2];
      s3 += q[d4 * 4 + 3] * kv[3];
    }
    float s = (s0 + s1) + (s2 + s3);
    s += bias_s[wid][(th - (k >> 3) + 7) * 15 + (tw - (k & 7) + 7)];
    if (SHIFT > 0 && mycode != code_s[k]) s -= 100.f;
    const float p = __expf(s);
    sum += p;
    #pragma unroll
    for (int d4 = 0; d4 < 8; ++d4){
      const f32x4v vv = *(const f32x4v*)&Vf[k][hb + d4 * 4];
      o[d4] += p * vv;
    }
  }
  const float inv = 1.f / sum;
  ushort* ob = outp + tok * 256 + head * 32;
  #pragma unroll
  for (int d4 = 0; d4 < 8; ++d4){
    ushort4 ov = { f2bf(o[d4][0] * inv), f2bf(o[d4][1] * inv),
                   f2bf(o[d4][2] * inv), f2bf(o[d4][3] * inv) };
    *(ushort4*)(ob + d4 * 4) = ov;
  }
}

extern "C" void kernel_launch(void* const* d_in, const int* in_sizes, int n_in,
                              void* d_out, int out_size, void* d_ws, size_t ws_size,
                              hipStream_t stream){
  const float* pcd    = (const float*)d_in[0];
  const float* img    = (const float*)d_in[1];
  const float* rd_w1  = (const float*)d_in[2];
  const float* rd_b1  = (const float*)d_in[3];
  const float* rd_lng = (const float*)d_in[4];
  const float* rd_lnb = (const float*)d_in[5];
  const float* rd_w2  = (const float*)d_in[6];
  const float* rd_b2  = (const float*)d_in[7];
  const float* n1g    = (const float*)d_in[8];
  const float* n1b    = (const float*)d_in[9];
  const float* qkv_w  = (const float*)d_in[10];
  const float* qkv_b  = (const float*)d_in[11];
  const float* rpb    = (const float*)d_in[12];
  const float* proj_w = (const float*)d_in[13];
  const float* proj_b = (const float*)d_in[14];
  const float* n2g    = (const float*)d_in[15];
  const float* n2b    = (const float*)d_in[16];
  const float* mlp_w1 = (const float*)d_in[17];
  const float* mlp_b1 = (const float*)d_in[18];
  const float* mlp_w2 = (const float*)d_in[19];
  const float* mlp_b2 = (const float*)d_in[20];

  char* ws = (char*)d_ws;
  ushort* w1b    = (ushort*)(ws + 0);                // 2048x512 bf16   2 MB
  ushort* w2g    = (ushort*)(ws + 2097152);          // 256x2048 (γ·w)  1 MB
  ushort* qkvwg  = (ushort*)(ws + 3145728);          // 2x768x256 (γ·w) 0.75 MB
  ushort* projwb = (ushort*)(ws + 3932160);          // 2x256x256       0.25 MB
  ushort* mlp1wg = (ushort*)(ws + 4194304);          // 2x1024x256 (γ·w) 1 MB
  ushort* mlp2wb = (ushort*)(ws + 5242880);          // 2x256x1024      1 MB
  float*  cvec   = (float*)(ws + 6291456);           // 32 KB c1/c2 pool
  float*  w2c1   = cvec,        *w2c2   = cvec + 256;
  float*  qkvc1  = cvec + 512,  *qkvc2  = cvec + 2048;   // 2x768 each
  float*  mlp1c1 = cvec + 3584, *mlp1c2 = cvec + 5632;   // 2x1024 each
  float*  stats  = (float*)(ws + 6324224);           // T x 2 f32  1 MB
  ushort* xr     = (ushort*)(ws + 7372800);          // residual, T x 256 bf16  67 MB
  char*   big    = ws + 74481664;                    // 268,435,456 B region
  ushort* A0     = (ushort*)big;                     // T x 512 bf16 (134 MB)
  ushort* X1c    = (ushort*)(big + 134217728);       // 32768 x 2048 (134 MB)
  ushort* qkvb   = (ushort*)big;                     // T x 768 (201 MB)
  ushort* attno  = (ushort*)(big + 201326592);       // T x 256 (67 MB)
  ushort* hidden = (ushort*)big;                     // T x 1024 (268 MB)
  float* xout = (float*)d_out;                       // final output f32
  // peak ws use = 74,481,664 + 268,435,456 = 342,917,120 B

  // ---- weight preprocessing ----
  cvtw_k<<<1024, 256, 0, stream>>>(rd_w1, w1b, 262144);
  cvtw_k<<<128,  256, 0, stream>>>(proj_w, projwb, 32768);
  cvtw_k<<<512,  256, 0, stream>>>(mlp_w2, mlp2wb, 131072);
  cvtwg_k<<<256, 64, 0, stream>>>(rd_w2, rd_lng, rd_lnb, w2g, w2c1, w2c2, 2048);
  for (int i = 0; i < 2; ++i){
    cvtwg_k<<<768, 64, 0, stream>>>(qkv_w + i * 196608, n1g + i * 256, n1b + i * 256,
        qkvwg + i * 196608, qkvc1 + i * 768, qkvc2 + i * 768, 256);
    cvtwg_k<<<1024, 64, 0, stream>>>(mlp_w1 + i * 262144, n2g + i * 256, n2b + i * 256,
        mlp1wg + i * 262144, mlp1c1 + i * 1024, mlp1c2 + i * 1024, 256);
  }
  concat_k<<<65536, 256, 0, stream>>>(pcd, img, A0);

  // ---- reduce block, chunked over M ----
  for (int c = 0; c < 4; ++c){
    const long off = (long)c * MCHUNK;
    gemm_k<1,1,0,false,2><<<4096, 256, 0, stream>>>(A0 + off * 512, w1b, rd_b1,
        nullptr, X1c, nullptr, nullptr, nullptr, nullptr, nullptr, 2048, 512, 16);
    rowstats_k<<<MCHUNK, 256, 0, stream>>>(X1c, stats + off * 2);
    gemm_k<0,1,0,true,2><<<512, 256, 0, stream>>>(X1c, w2g, rd_b2,
        nullptr, xr + off * 256, nullptr, nullptr,
        stats + off * 2, w2c1, w2c2, 256, 2048, 2);
  }
  stats256b_k<<<TOK / 4, 256, 0, stream>>>(xr, stats);

  // ---- Swin layers ----
  for (int i = 0; i < 2; ++i){
    gemm_k<0,1,0,true,2><<<6144, 256, 0, stream>>>(xr, qkvwg + i * 196608, qkv_b + i * 768,
        nullptr, qkvb, nullptr, nullptr, stats, qkvc1 + i * 768, qkvc2 + i * 768,
        768, 256, 6);
    if (i == 0)
      attn_k<0><<<4096, 256, 0, stream>>>(qkvb, rpb, attno);
    else
      attn_k<4><<<4096, 256, 0, stream>>>(qkvb, rpb + 1800, attno);
    gemm_k<0,1,1,false,2><<<2048, 256, 0, stream>>>(attno, projwb + i * 65536,
        proj_b + i * 256, nullptr, xr, xr, nullptr, nullptr, nullptr, nullptr, 256, 256, 2);
    stats256b_k<<<TOK / 4, 256, 0, stream>>>(xr, stats);
    gemm_k<2,1,0,true,2><<<8192, 256, 0, stream>>>(xr, mlp1wg + i * 262144,
        mlp_b1 + i * 1024, nullptr, hidden, nullptr, nullptr,
        stats, mlp1c1 + i * 1024, mlp1c2 + i * 1024, 1024, 256, 8);
    if (i == 0){
      gemm_k<0,1,1,false,2><<<2048, 256, 0, stream>>>(hidden, mlp2wb, mlp_b2,
          nullptr, xr, xr, nullptr, nullptr, nullptr, nullptr, 256, 1024, 2);
      stats256b_k<<<TOK / 4, 256, 0, stream>>>(xr, stats);
    } else {
      gemm_k<0,0,2,false,2><<<2048, 256, 0, stream>>>(hidden, mlp2wb + 262144,
          mlp_b2 + 256, xout, nullptr, xr, pcd, nullptr, nullptr, nullptr, 256, 1024, 2);
    }
  }
}